// Round 1
// baseline (514.785 us; speedup 1.0000x reference)
//
#include <hip/hip_runtime.h>
#include <math.h>

// FermiNet_spin: N=1024, DIM=3, NP=5, NF=5, L=10, DEPTH=4, SPSIZE=64, TPSIZE=32
// TPSIZE0=35, FSIZE0=79, FSIZE=256.
//
// Strategy: tp-stream (the O(N^2) part) never depends on sp-stream, and the sp
// stream only consumes per-i up/dn SUMS of tp0..tp3. So k_tp computes the whole
// tp chain per pair in registers and emits only the 262 sums per i (never
// materializing the 140MB tp tensor). The sp chain is a sequence of tiny kernels.

#define INV512f 0.001953125f

__device__ __forceinline__ float sp_f(float v) {
    // softplus, stable: max(v,0) + log1p(exp(-|v|))
    return fmaxf(v, 0.0f) + __logf(1.0f + __expf(-fabsf(v)));
}

__device__ __forceinline__ float wred64(float v) {
    v += __shfl_xor(v, 32, 64);
    v += __shfl_xor(v, 16, 64);
    v += __shfl_xor(v, 8, 64);
    v += __shfl_xor(v, 4, 64);
    v += __shfl_xor(v, 2, 64);
    v += __shfl_xor(v, 1, 64);
    return v;
}

// ---------------------------------------------------------------------------
// k_tp: block = (i, half) — one 64-lane wave; lane iterates 8 j's in the half.
// Computes tp0 (35 feats) -> tp1 -> tp2 -> tp3 per pair fully in registers,
// accumulating per-lane sums, then wave-reduces and stores sums to M[i][262]:
//   [0..34]=sum0_up|dn(per half), [70..]=sum1, [134..]=sum2, [198..]=sum3
//   (up at +0, dn at +35 / +32 within each section, selected by `half`)
// ---------------------------------------------------------------------------
__global__ __launch_bounds__(64, 2) void k_tp(
    const float* __restrict__ x,
    const float* __restrict__ Wt0, const float* __restrict__ bt0,
    const float* __restrict__ Wt,  const float* __restrict__ bt,
    float* __restrict__ M)
{
    const int lane = threadIdx.x;
    const int i    = blockIdx.x >> 1;
    const int half = blockIdx.x & 1;

    const float xi0 = x[3*i+0];
    const float xi1 = x[3*i+1];
    const float xi2 = x[3*i+2];

    float A0[35];
    float A1[32], A2[32], A3[32];
#pragma unroll
    for (int f = 0; f < 35; ++f) A0[f] = 0.0f;
#pragma unroll
    for (int f = 0; f < 32; ++f) { A1[f] = 0.0f; A2[f] = 0.0f; A3[f] = 0.0f; }

#pragma unroll 1
    for (int it = 0; it < 8; ++it) {
        const int j = (half << 9) + (it << 6) + lane;
        const float r0 = xi0 - x[3*j+0];
        const float r1 = xi1 - x[3*j+1];
        const float r2 = xi2 - x[3*j+2];

        const float PIL  = 0.31415926535f;   // pi/L
        const float TPIL = 0.62831853071f;   // 2*pi/L

        float tp0[35];
        {
            // dij = || sin(pi*rij/L) ||  (diagonal: r=0 -> d=0, matches ref)
            float s0 = __sinf(PIL * r0);
            float s1 = __sinf(PIL * r1);
            float s2 = __sinf(PIL * r2);
            float d2 = s0*s0 + s1*s1 + s2*s2;
            float d1 = sqrtf(d2);
            tp0[0] = d1;
            tp0[1] = d2;
            tp0[2] = d2 * d1;
            tp0[3] = d2 * d2;
            tp0[4] = d2 * d2 * d1;
        }
        // Fourier orders 1..5 via complex recurrence from order 1
        float c1x = __cosf(TPIL * r0), s1x = __sinf(TPIL * r0);
        float c1y = __cosf(TPIL * r1), s1y = __sinf(TPIL * r1);
        float c1z = __cosf(TPIL * r2), s1z = __sinf(TPIL * r2);
        float cx = c1x, sx = s1x;
        float cy = c1y, sy = s1y;
        float cz = c1z, sz = s1z;
        tp0[5] = cx; tp0[6] = cy; tp0[7] = cz;
        tp0[8] = sx; tp0[9] = sy; tp0[10] = sz;
#pragma unroll
        for (int k = 2; k <= 5; ++k) {
            float ncx = cx*c1x - sx*s1x, nsx = sx*c1x + cx*s1x;
            float ncy = cy*c1y - sy*s1y, nsy = sy*c1y + cy*s1y;
            float ncz = cz*c1z - sz*s1z, nsz = sz*c1z + cz*s1z;
            cx = ncx; sx = nsx; cy = ncy; sy = nsy; cz = ncz; sz = nsz;
            const int b = 5 + (k-1)*6;
            tp0[b+0] = cx; tp0[b+1] = cy; tp0[b+2] = cz;
            tp0[b+3] = sx; tp0[b+4] = sy; tp0[b+5] = sz;
        }
#pragma unroll
        for (int f = 0; f < 35; ++f) A0[f] += tp0[f];

        // tp1 = softplus(tp0 @ Wt0 + bt0)        (35x32)
        float t1[32];
#pragma unroll
        for (int c = 0; c < 32; ++c) t1[c] = bt0[c];
#pragma unroll
        for (int k = 0; k < 35; ++k) {
            const float v = tp0[k];
#pragma unroll
            for (int c = 0; c < 32; ++c) t1[c] = fmaf(v, Wt0[k*32 + c], t1[c]);
        }
#pragma unroll
        for (int c = 0; c < 32; ++c) { t1[c] = sp_f(t1[c]); A1[c] += t1[c]; }

        // tp2 = tp1 + softplus(tp1 @ Wt[0] + bt[0])   (32x32)
        float t2[32];
#pragma unroll
        for (int c = 0; c < 32; ++c) t2[c] = bt[c];
#pragma unroll
        for (int k = 0; k < 32; ++k) {
            const float v = t1[k];
#pragma unroll
            for (int c = 0; c < 32; ++c) t2[c] = fmaf(v, Wt[k*32 + c], t2[c]);
        }
#pragma unroll
        for (int c = 0; c < 32; ++c) { t2[c] = t1[c] + sp_f(t2[c]); A2[c] += t2[c]; }

        // tp3 = tp2 + softplus(tp2 @ Wt[1] + bt[1])   (32x32)
        float t3[32];
#pragma unroll
        for (int c = 0; c < 32; ++c) t3[c] = bt[32 + c];
#pragma unroll
        for (int k = 0; k < 32; ++k) {
            const float v = t2[k];
#pragma unroll
            for (int c = 0; c < 32; ++c) t3[c] = fmaf(v, Wt[1024 + k*32 + c], t3[c]);
        }
#pragma unroll
        for (int c = 0; c < 32; ++c) { t3[c] = t2[c] + sp_f(t3[c]); A3[c] += t3[c]; }
    }

    float* __restrict__ Mi = M + (size_t)i * 262;
#pragma unroll
    for (int f = 0; f < 35; ++f) {
        float t = wred64(A0[f]);
        if (lane == 0) Mi[half*35 + f] = t;
    }
#pragma unroll
    for (int f = 0; f < 32; ++f) {
        float t = wred64(A1[f]);
        if (lane == 0) Mi[70 + half*32 + f] = t;
    }
#pragma unroll
    for (int f = 0; f < 32; ++f) {
        float t = wred64(A2[f]);
        if (lane == 0) Mi[134 + half*32 + f] = t;
    }
#pragma unroll
    for (int f = 0; f < 32; ++f) {
        float t = wred64(A3[f]);
        if (lane == 0) Mi[198 + half*32 + f] = t;
    }
}

// ---------------------------------------------------------------------------
// sp1 = softplus(f0 @ W_sp0 + b_sp0); f0 = [0 x9, m0up/512, m0dn/512]
// thread = (row ii, col c); 4 rows per 256-thread block
// ---------------------------------------------------------------------------
__global__ __launch_bounds__(256) void k_sp1(
    const float* __restrict__ M,
    const float* __restrict__ W, const float* __restrict__ b,
    float* __restrict__ sp1)
{
    const int c  = threadIdx.x & 63;
    const int ii = (blockIdx.x << 2) + (threadIdx.x >> 6);
    const float* __restrict__ m = M + (size_t)ii * 262;
    float acc = b[c];
#pragma unroll
    for (int f = 0; f < 35; ++f)
        acc = fmaf(m[f] * INV512f, W[(9 + f)*64 + c], acc);
#pragma unroll
    for (int f = 0; f < 35; ++f)
        acc = fmaf(m[35 + f] * INV512f, W[(44 + f)*64 + c], acc);
    sp1[ii*64 + c] = sp_f(acc);
}

// column sums of sp over rows [h*512, h*512+512) -> out[h*64 + c]
__global__ __launch_bounds__(256) void k_colsum(
    const float* __restrict__ sp, float* __restrict__ out)
{
    const int h = blockIdx.x;
    const int c = threadIdx.x & 63;
    const int w = threadIdx.x >> 6;
    float acc = 0.0f;
    for (int r = w; r < 512; r += 4)
        acc += sp[(h*512 + r)*64 + c];
    __shared__ float red[4][64];
    red[w][c] = acc;
    __syncthreads();
    if (w == 0)
        out[h*64 + c] = red[0][c] + red[1][c] + red[2][c] + red[3][c];
}

// spout = spin + softplus(f @ W + b)
// f = [spin_i(64), sum_up/512(64), sum_dn/512(64), m_up/512(32), m_dn/512(32)]
__global__ __launch_bounds__(256) void k_spmid(
    const float* __restrict__ spin, const float* __restrict__ M, int moff,
    const float* __restrict__ S,
    const float* __restrict__ W, const float* __restrict__ b,
    float* __restrict__ spout)
{
    const int c  = threadIdx.x & 63;
    const int ii = (blockIdx.x << 2) + (threadIdx.x >> 6);
    const float* __restrict__ si = spin + ii*64;
    const float* __restrict__ m  = M + (size_t)ii*262 + moff;
    float acc = b[c];
#pragma unroll 4
    for (int k = 0; k < 64; ++k) acc = fmaf(si[k],            W[k*64 + c],        acc);
#pragma unroll 4
    for (int k = 0; k < 64; ++k) acc = fmaf(S[k]    * INV512f, W[(64 + k)*64 + c],  acc);
#pragma unroll 4
    for (int k = 0; k < 64; ++k) acc = fmaf(S[64+k] * INV512f, W[(128 + k)*64 + c], acc);
#pragma unroll 4
    for (int k = 0; k < 32; ++k) acc = fmaf(m[k]    * INV512f, W[(192 + k)*64 + c], acc);
#pragma unroll 4
    for (int k = 0; k < 32; ++k) acc = fmaf(m[32+k] * INV512f, W[(224 + k)*64 + c], acc);
    spout[ii*64 + c] = si[c] + sp_f(acc);
}

// out = x + sp4 @ W_final + b_final   (1024x3)
__global__ __launch_bounds__(256) void k_final(
    const float* __restrict__ sp4, const float* __restrict__ x,
    const float* __restrict__ Wf, const float* __restrict__ bf,
    float* __restrict__ out)
{
    const int g = blockIdx.x * 256 + threadIdx.x;   // 0..3071
    const int i = g / 3;
    const int d = g - i * 3;
    float acc = x[g] + bf[d];
#pragma unroll 8
    for (int c = 0; c < 64; ++c)
        acc = fmaf(sp4[i*64 + c], Wf[c*3 + d], acc);
    out[g] = acc;
}

extern "C" void kernel_launch(void* const* d_in, const int* in_sizes, int n_in,
                              void* d_out, int out_size, void* d_ws, size_t ws_size,
                              hipStream_t stream)
{
    const float* x    = (const float*)d_in[0];
    const float* Wsp0 = (const float*)d_in[1];
    const float* bsp0 = (const float*)d_in[2];
    const float* Wsp  = (const float*)d_in[3];   // (3, 256, 64)
    const float* bsp  = (const float*)d_in[4];   // (3, 64)
    const float* Wtp0 = (const float*)d_in[5];   // (35, 32)
    const float* btp0 = (const float*)d_in[6];
    const float* Wtp  = (const float*)d_in[7];   // (2, 32, 32)
    const float* btp  = (const float*)d_in[8];   // (2, 32)
    const float* Wfin = (const float*)d_in[9];   // (64, 3)
    const float* bfin = (const float*)d_in[10];
    float* out = (float*)d_out;
    float* ws  = (float*)d_ws;

    // workspace layout (floats)
    float* M   = ws;              // 1024*262 = 268288
    float* SP1 = ws + 268288;     // 1024*64
    float* SP2 = ws + 333824;
    float* SP3 = ws + 399360;
    float* SP4 = ws + 464896;
    float* S1  = ws + 530432;     // 128
    float* S2  = ws + 530560;
    float* S3  = ws + 530688;     // end: 530816 floats (~2.1 MB)

    k_tp<<<dim3(2048), dim3(64), 0, stream>>>(x, Wtp0, btp0, Wtp, btp, M);

    k_sp1<<<dim3(256), dim3(256), 0, stream>>>(M, Wsp0, bsp0, SP1);
    k_colsum<<<dim3(2), dim3(256), 0, stream>>>(SP1, S1);
    k_spmid<<<dim3(256), dim3(256), 0, stream>>>(SP1, M, 70,  S1, Wsp,          bsp,       SP2);
    k_colsum<<<dim3(2), dim3(256), 0, stream>>>(SP2, S2);
    k_spmid<<<dim3(256), dim3(256), 0, stream>>>(SP2, M, 134, S2, Wsp + 16384,  bsp + 64,  SP3);
    k_colsum<<<dim3(2), dim3(256), 0, stream>>>(SP3, S3);
    k_spmid<<<dim3(256), dim3(256), 0, stream>>>(SP3, M, 198, S3, Wsp + 32768,  bsp + 128, SP4);
    k_final<<<dim3(12), dim3(256), 0, stream>>>(SP4, x, Wfin, bfin, out);
}

// Round 3
// 391.876 us; speedup vs baseline: 1.3136x; 1.3136x over previous
//
#include <hip/hip_runtime.h>
#include <math.h>

// FermiNet_spin: N=1024, DIM=3, NP=5, NF=5, L=10, DEPTH=4, SPSIZE=64, TPSIZE=32
// Non-cooperative multi-kernel pipeline:
//   k_cs  : per-particle Fourier basis cs[i][30] + per-quarter sums CSp
//   k_tp  : O(N^2) pair stream fully in registers; only per-(i,half) SUMS kept.
//           Fourier part of tp0 sums is NOT accumulated per-pair — it is
//           reconstructed analytically in k_s1 from cs/CSp (trig identity),
//           cutting live accumulators 131 -> 101 (5 d-powers + 3x32 layers).
//   k_s1  : sp1 = softplus(f0 @ Wsp0[9:] + b)  (first 9 rows: sp=0)
//   k_smid: sp_{l+1} = sp_l + softplus(f @ W + b), colsum partials fused
//   k_slast: last sp layer + final 64x3 projection
#define INV512f 0.001953125f
#define MSTR 208
#define PILf  0.314159265358979324f
#define TPILf 0.628318530717958648f

__device__ __forceinline__ float sp_f(float v) {
    // softplus, stable: max(v,0) + log1p(exp(-|v|))
    return fmaxf(v, 0.0f) + __logf(1.0f + __expf(-fabsf(v)));
}

__device__ __forceinline__ float wred64(float v) {
    v += __shfl_xor(v, 32, 64);
    v += __shfl_xor(v, 16, 64);
    v += __shfl_xor(v, 8, 64);
    v += __shfl_xor(v, 4, 64);
    v += __shfl_xor(v, 2, 64);
    v += __shfl_xor(v, 1, 64);
    return v;
}

// ---------------------------------------------------------------------------
__global__ __launch_bounds__(256) void k_cs(
    const float* __restrict__ x, float* __restrict__ cs, float* __restrict__ CSp)
{
    __shared__ float wp[4][30];
    const int tid = threadIdx.x;
    const int i = (blockIdx.x << 8) + tid;
    float v[30];
    {
        float a0 = TPILf * x[3*i+0], a1 = TPILf * x[3*i+1], a2 = TPILf * x[3*i+2];
        float c1x = __cosf(a0), s1x = __sinf(a0);
        float c1y = __cosf(a1), s1y = __sinf(a1);
        float c1z = __cosf(a2), s1z = __sinf(a2);
        float cx = c1x, sx = s1x, cy = c1y, sy = s1y, cz = c1z, sz = s1z;
        v[0]=cx; v[1]=cy; v[2]=cz; v[3]=sx; v[4]=sy; v[5]=sz;
#pragma unroll
        for (int k = 2; k <= 5; ++k) {
            float ncx = cx*c1x - sx*s1x, nsx = sx*c1x + cx*s1x;
            float ncy = cy*c1y - sy*s1y, nsy = sy*c1y + cy*s1y;
            float ncz = cz*c1z - sz*s1z, nsz = sz*c1z + cz*s1z;
            cx=ncx; sx=nsx; cy=ncy; sy=nsy; cz=ncz; sz=nsz;
            const int base = (k-1)*6;
            v[base+0]=cx; v[base+1]=cy; v[base+2]=cz;
            v[base+3]=sx; v[base+4]=sy; v[base+5]=sz;
        }
    }
#pragma unroll
    for (int f = 0; f < 30; ++f) cs[(i << 5) + f] = v[f];
    const int w = tid >> 6;
#pragma unroll
    for (int f = 0; f < 30; ++f) {
        float t = wred64(v[f]);
        if ((tid & 63) == 0) wp[w][f] = t;
    }
    __syncthreads();
    if (tid < 30)
        CSp[(blockIdx.x << 5) + tid] = wp[0][tid] + wp[1][tid] + wp[2][tid] + wp[3][tid];
}

// ---------------------------------------------------------------------------
// k_tp: block = one wave = (i, half); lane walks 8 j's of the half.
// M[i][0..9]  : d-power sums (5 up, 5 dn)
// M[i][10..73]: tp1 sums (32 up, 32 dn);  [74..137]: tp2;  [138..201]: tp3
// ---------------------------------------------------------------------------
__global__ __attribute__((amdgpu_flat_work_group_size(64, 64), amdgpu_waves_per_eu(1, 2)))
void k_tp(const float* __restrict__ x,
          const float* __restrict__ Wt0, const float* __restrict__ bt0,
          const float* __restrict__ Wt,  const float* __restrict__ bt,
          float* __restrict__ M)
{
    const int lane = threadIdx.x;
    const int i    = blockIdx.x >> 1;
    const int half = blockIdx.x & 1;

    const float xi0 = x[3*i+0];
    const float xi1 = x[3*i+1];
    const float xi2 = x[3*i+2];

    float A0[5], A1[32], A2[32], A3[32];
#pragma unroll
    for (int p = 0; p < 5; ++p) A0[p] = 0.f;
#pragma unroll
    for (int c = 0; c < 32; ++c) { A1[c]=0.f; A2[c]=0.f; A3[c]=0.f; }

#pragma unroll 1
    for (int it = 0; it < 8; ++it) {
        const int j = (half << 9) + (it << 6) + lane;
        const float r0 = xi0 - x[3*j+0];
        const float r1 = xi1 - x[3*j+1];
        const float r2 = xi2 - x[3*j+2];

        float t1[32];
        {
            // d-powers, accumulated into A0 and rank-1-folded into t1 directly
            float s0 = __sinf(PILf*r0), s1 = __sinf(PILf*r1), s2 = __sinf(PILf*r2);
            float d2 = s0*s0 + s1*s1 + s2*s2;
            float d1 = sqrtf(d2);
            float p0 = d1, p1 = d2, p2 = d2*d1, p3 = d2*d2, p4 = d2*d2*d1;
            A0[0]+=p0; A0[1]+=p1; A0[2]+=p2; A0[3]+=p3; A0[4]+=p4;
#pragma unroll
            for (int c = 0; c < 32; ++c) {
                float acc = bt0[c];
                acc = fmaf(p0, Wt0[0*32 + c], acc);
                acc = fmaf(p1, Wt0[1*32 + c], acc);
                acc = fmaf(p2, Wt0[2*32 + c], acc);
                acc = fmaf(p3, Wt0[3*32 + c], acc);
                acc = fmaf(p4, Wt0[4*32 + c], acc);
                t1[c] = acc;
            }
        }
        // Fourier features generated incrementally, folded into t1 (never stored)
        {
            float c1x = __cosf(TPILf*r0), s1x = __sinf(TPILf*r0);
            float c1y = __cosf(TPILf*r1), s1y = __sinf(TPILf*r1);
            float c1z = __cosf(TPILf*r2), s1z = __sinf(TPILf*r2);
            float cx=c1x, sx=s1x, cy=c1y, sy=s1y, cz=c1z, sz=s1z;
#pragma unroll
            for (int k = 1; k <= 5; ++k) {
                if (k > 1) {
                    float ncx = cx*c1x - sx*s1x, nsx = sx*c1x + cx*s1x;
                    float ncy = cy*c1y - sy*s1y, nsy = sy*c1y + cy*s1y;
                    float ncz = cz*c1z - sz*s1z, nsz = sz*c1z + cz*s1z;
                    cx=ncx; sx=nsx; cy=ncy; sy=nsy; cz=ncz; sz=nsz;
                }
                const int base = (5 + (k-1)*6) * 32;
#pragma unroll
                for (int c = 0; c < 32; ++c) {
                    float acc = t1[c];
                    acc = fmaf(cx, Wt0[base +   0 + c], acc);
                    acc = fmaf(cy, Wt0[base +  32 + c], acc);
                    acc = fmaf(cz, Wt0[base +  64 + c], acc);
                    acc = fmaf(sx, Wt0[base +  96 + c], acc);
                    acc = fmaf(sy, Wt0[base + 128 + c], acc);
                    acc = fmaf(sz, Wt0[base + 160 + c], acc);
                    t1[c] = acc;
                }
            }
        }
#pragma unroll
        for (int c = 0; c < 32; ++c) { t1[c] = sp_f(t1[c]); A1[c] += t1[c]; }

        // tp2 = tp1 + softplus(tp1 @ Wt[0] + bt[0])
        float t2[32];
#pragma unroll
        for (int c = 0; c < 32; ++c) t2[c] = bt[c];
#pragma unroll
        for (int k = 0; k < 32; ++k) {
            const float v = t1[k];
#pragma unroll
            for (int c = 0; c < 32; ++c) t2[c] = fmaf(v, Wt[k*32 + c], t2[c]);
        }
#pragma unroll
        for (int c = 0; c < 32; ++c) { t2[c] = t1[c] + sp_f(t2[c]); A2[c] += t2[c]; }

        // tp3 = tp2 + softplus(tp2 @ Wt[1] + bt[1])
        float t3[32];
#pragma unroll
        for (int c = 0; c < 32; ++c) t3[c] = bt[32 + c];
#pragma unroll
        for (int k = 0; k < 32; ++k) {
            const float v = t2[k];
#pragma unroll
            for (int c = 0; c < 32; ++c) t3[c] = fmaf(v, Wt[1024 + k*32 + c], t3[c]);
        }
#pragma unroll
        for (int c = 0; c < 32; ++c) { t3[c] = t2[c] + sp_f(t3[c]); A3[c] += t3[c]; }
    }

    float* __restrict__ Mi = M + (size_t)i * MSTR;
#pragma unroll
    for (int p = 0; p < 5; ++p) {
        float t = wred64(A0[p]);
        if (lane == 0) Mi[half*5 + p] = t;
    }
#pragma unroll
    for (int c = 0; c < 32; ++c) {
        float t = wred64(A1[c]);
        if (lane == 0) Mi[10 + half*32 + c] = t;
    }
#pragma unroll
    for (int c = 0; c < 32; ++c) {
        float t = wred64(A2[c]);
        if (lane == 0) Mi[74 + half*32 + c] = t;
    }
#pragma unroll
    for (int c = 0; c < 32; ++c) {
        float t = wred64(A3[c]);
        if (lane == 0) Mi[138 + half*32 + c] = t;
    }
}

// ---------------------------------------------------------------------------
// k_s1: sp1 = softplus(f0 @ Wsp0 + b); writes SP1 and per-block colsum partials
// f0 tp-mean features: d-powers from M, Fourier reconstructed from cs/CSp.
// ---------------------------------------------------------------------------
__global__ __launch_bounds__(256) void k_s1(
    const float* __restrict__ M, const float* __restrict__ cs,
    const float* __restrict__ CSp,
    const float* __restrict__ W, const float* __restrict__ bv,
    float* __restrict__ SP1, float* __restrict__ P1)
{
    __shared__ float CSsh[2][30];
    __shared__ float feat[4][70];
    __shared__ float red[4][64];
    const int tid = threadIdx.x;
    const int c = tid & 63, g = tid >> 6;
    const int ii = (blockIdx.x << 2) + g;

    if (tid < 60) {
        int hh = tid / 30, f = tid - 30*hh;
        CSsh[hh][f] = CSp[(hh << 6) + f] + CSp[(hh << 6) + 32 + f];
    }
    __syncthreads();
#pragma unroll
    for (int pass = 0; pass < 2; ++pass) {
        const int f = (pass == 0) ? c : 64 + c;
        if (pass == 0 || c < 6) {
            const int sec = (f >= 35) ? 1 : 0;
            const int idx = f - 35*sec;
            float v;
            if (idx < 5) {
                v = M[(size_t)ii * MSTR + sec*5 + idx];
            } else {
                const int gg = idx - 5;
                const int k = gg / 6;
                const int m = gg - 6*k;
                const int dim = (m < 3) ? m : m - 3;
                const float cth = cs[(ii << 5) + k*6 + dim];
                const float sth = cs[(ii << 5) + k*6 + 3 + dim];
                const float Cc  = CSsh[sec][k*6 + dim];
                const float Sc  = CSsh[sec][k*6 + 3 + dim];
                v = (m < 3) ? fmaf(cth, Cc, sth*Sc) : (sth*Cc - cth*Sc);
            }
            feat[g][f] = v * INV512f;
        }
    }
    __syncthreads();
    float acc = bv[c];
#pragma unroll 7
    for (int f = 0; f < 70; ++f)
        acc = fmaf(feat[g][f], W[(9 + f)*64 + c], acc);
    float s = sp_f(acc);
    SP1[(ii << 6) + c] = s;
    red[g][c] = s;
    __syncthreads();
    if (g == 0)
        P1[(blockIdx.x << 6) + c] = red[0][c] + red[1][c] + red[2][c] + red[3][c];
}

// ---------------------------------------------------------------------------
// spmid core: s = sp_in + softplus([sp_i, up_mean, dn_mean, tpmean] @ W + b)
// ---------------------------------------------------------------------------
__device__ __forceinline__ float spmid_core(
    int b, int tid,
    const float* __restrict__ SPin, const float* __restrict__ Pin,
    const float* __restrict__ M, int moff,
    const float* __restrict__ W, const float* __restrict__ bv,
    float Sred[2][4][64], float Ssh[2][64], float si[4][64], float featm[4][64])
{
    const int c = tid & 63, g = tid >> 6;
    const int ii = (b << 2) + g;
    float pu = 0.f, pd = 0.f;
#pragma unroll 4
    for (int bb = g; bb < 128; bb += 4) {
        pu += Pin[(bb << 6) + c];
        pd += Pin[((128 + bb) << 6) + c];
    }
    si[g][c]    = SPin[(ii << 6) + c];
    featm[g][c] = M[(size_t)ii * MSTR + moff + c] * INV512f;
    Sred[0][g][c] = pu; Sred[1][g][c] = pd;
    __syncthreads();
    if (g < 2)
        Ssh[g][c] = (Sred[g][0][c] + Sred[g][1][c] + Sred[g][2][c] + Sred[g][3][c]) * INV512f;
    __syncthreads();
    float acc = bv[c];
#pragma unroll 8
    for (int k = 0; k < 64; ++k) acc = fmaf(si[g][k],    W[(k << 6) + c],         acc);
#pragma unroll 8
    for (int k = 0; k < 64; ++k) acc = fmaf(Ssh[0][k],   W[((64 + k) << 6) + c],  acc);
#pragma unroll 8
    for (int k = 0; k < 64; ++k) acc = fmaf(Ssh[1][k],   W[((128 + k) << 6) + c], acc);
#pragma unroll 8
    for (int k = 0; k < 64; ++k) acc = fmaf(featm[g][k], W[((192 + k) << 6) + c], acc);
    return si[g][c] + sp_f(acc);
}

__global__ __launch_bounds__(256) void k_smid(
    const float* __restrict__ SPin, const float* __restrict__ Pin,
    const float* __restrict__ M, int moff,
    const float* __restrict__ W, const float* __restrict__ bv,
    float* __restrict__ SPout, float* __restrict__ Pout)
{
    __shared__ float Sred[2][4][64];
    __shared__ float Ssh[2][64];
    __shared__ float si[4][64];
    __shared__ float featm[4][64];
    const int tid = threadIdx.x;
    float s = spmid_core(blockIdx.x, tid, SPin, Pin, M, moff, W, bv, Sred, Ssh, si, featm);
    const int c = tid & 63, g = tid >> 6;
    SPout[(((blockIdx.x << 2) + g) << 6) + c] = s;
    __syncthreads();
    Sred[0][g][c] = s;
    __syncthreads();
    if (g == 0)
        Pout[(blockIdx.x << 6) + c] = Sred[0][0][c] + Sred[0][1][c] + Sred[0][2][c] + Sred[0][3][c];
}

__global__ __launch_bounds__(256) void k_slast(
    const float* __restrict__ SPin, const float* __restrict__ Pin,
    const float* __restrict__ M, int moff,
    const float* __restrict__ W, const float* __restrict__ bv,
    const float* __restrict__ x,
    const float* __restrict__ Wfin, const float* __restrict__ bfin,
    float* __restrict__ out)
{
    __shared__ float Sred[2][4][64];
    __shared__ float Ssh[2][64];
    __shared__ float si[4][64];
    __shared__ float featm[4][64];
    const int tid = threadIdx.x;
    float s = spmid_core(blockIdx.x, tid, SPin, Pin, M, moff, W, bv, Sred, Ssh, si, featm);
    const int c = tid & 63, g = tid >> 6;
    __syncthreads();
    si[g][c] = s;   // sp4 rows
    __syncthreads();
    if (tid < 12) {
        const int r = tid / 3, d = tid - 3*r;
        const int io = (blockIdx.x << 2) + r;
        float acc = x[3*io + d] + bfin[d];
#pragma unroll 16
        for (int k = 0; k < 64; ++k) acc = fmaf(si[r][k], Wfin[3*k + d], acc);
        out[3*io + d] = acc;
    }
}

extern "C" void kernel_launch(void* const* d_in, const int* in_sizes, int n_in,
                              void* d_out, int out_size, void* d_ws, size_t ws_size,
                              hipStream_t stream)
{
    const float* x    = (const float*)d_in[0];
    const float* Wsp0 = (const float*)d_in[1];
    const float* bsp0 = (const float*)d_in[2];
    const float* Wsp  = (const float*)d_in[3];   // (3, 256, 64)
    const float* bsp  = (const float*)d_in[4];   // (3, 64)
    const float* Wtp0 = (const float*)d_in[5];   // (35, 32)
    const float* btp0 = (const float*)d_in[6];
    const float* Wtp  = (const float*)d_in[7];   // (2, 32, 32)
    const float* btp  = (const float*)d_in[8];   // (2, 32)
    const float* Wfin = (const float*)d_in[9];   // (64, 3)
    const float* bfin = (const float*)d_in[10];
    float* out = (float*)d_out;
    float* ws  = (float*)d_ws;

    // workspace layout (floats); SP3/P3 alias SP1/P1 (dead after S2)
    float* cs  = ws;              // 1024*32
    float* CSp = ws + 32768;      // 4*32
    float* M   = ws + 32896;      // 1024*208
    float* SP1 = ws + 245888;     // 1024*64
    float* SP2 = ws + 311424;     // 1024*64
    float* P1  = ws + 376960;     // 256*64
    float* P2  = ws + 393344;     // 256*64  (end 409728 floats = 1.64 MB)

    k_cs<<<dim3(4),   dim3(256), 0, stream>>>(x, cs, CSp);
    k_tp<<<dim3(2048), dim3(64), 0, stream>>>(x, Wtp0, btp0, Wtp, btp, M);
    k_s1<<<dim3(256), dim3(256), 0, stream>>>(M, cs, CSp, Wsp0, bsp0, SP1, P1);
    k_smid<<<dim3(256), dim3(256), 0, stream>>>(SP1, P1, M, 10,  Wsp,         bsp,       SP2, P2);
    k_smid<<<dim3(256), dim3(256), 0, stream>>>(SP2, P2, M, 74,  Wsp + 16384, bsp + 64,  SP1, P1);
    k_slast<<<dim3(256), dim3(256), 0, stream>>>(SP1, P1, M, 138, Wsp + 32768, bsp + 128,
                                                 x, Wfin, bfin, out);
}

// Round 4
// 353.762 us; speedup vs baseline: 1.4552x; 1.1077x over previous
//
#include <hip/hip_runtime.h>
#include <hip/hip_fp16.h>
#include <math.h>

// FermiNet_spin: N=1024, DIM=3, NP=5, NF=5, L=10, DEPTH=4, SPSIZE=64, TPSIZE=32
// Pipeline:
//   k_cs  : per-particle Fourier basis cs[i][30] + per-quarter sums CSp
//   k_tp  : O(N^2) pair stream fully in registers; only per-(i,half) SUMS kept.
//           Accumulators packed __half2 (96 f32 -> 51 regs) so total live regs
//           fit the arch-VGPR file => no AGPR shuttle (round-3 bottleneck).
//   k_s1  : sp1 = softplus(f0 @ Wsp0[9:] + b); Fourier tp-sums reconstructed
//           analytically from cs/CSp (trig identity).
//   k_smid: sp_{l+1} = sp_l + softplus(f @ W + b), colsum partials fused
//   k_slast: last sp layer + final 64x3 projection
#define INV512f 0.001953125f
#define MSTR 208
#define TPILf 0.628318530717958648f

__device__ __forceinline__ float sp_f(float v) {
    // softplus, stable: max(v,0) + log1p(exp(-|v|))
    return fmaxf(v, 0.0f) + __logf(1.0f + __expf(-fabsf(v)));
}

__device__ __forceinline__ float wred64(float v) {
    v += __shfl_xor(v, 32, 64);
    v += __shfl_xor(v, 16, 64);
    v += __shfl_xor(v, 8, 64);
    v += __shfl_xor(v, 4, 64);
    v += __shfl_xor(v, 2, 64);
    v += __shfl_xor(v, 1, 64);
    return v;
}

__device__ __forceinline__ __half2 wred64h(__half2 v) {
#pragma unroll
    for (int m = 32; m; m >>= 1) {
        int o = __shfl_xor(*reinterpret_cast<int*>(&v), m, 64);
        v = __hadd2(v, *reinterpret_cast<__half2*>(&o));
    }
    return v;
}

// ---------------------------------------------------------------------------
__global__ __launch_bounds__(256) void k_cs(
    const float* __restrict__ x, float* __restrict__ cs, float* __restrict__ CSp)
{
    __shared__ float wp[4][30];
    const int tid = threadIdx.x;
    const int i = (blockIdx.x << 8) + tid;
    float v[30];
    {
        float a0 = TPILf * x[3*i+0], a1 = TPILf * x[3*i+1], a2 = TPILf * x[3*i+2];
        float c1x = __cosf(a0), s1x = __sinf(a0);
        float c1y = __cosf(a1), s1y = __sinf(a1);
        float c1z = __cosf(a2), s1z = __sinf(a2);
        float cx = c1x, sx = s1x, cy = c1y, sy = s1y, cz = c1z, sz = s1z;
        v[0]=cx; v[1]=cy; v[2]=cz; v[3]=sx; v[4]=sy; v[5]=sz;
#pragma unroll
        for (int k = 2; k <= 5; ++k) {
            float ncx = cx*c1x - sx*s1x, nsx = sx*c1x + cx*s1x;
            float ncy = cy*c1y - sy*s1y, nsy = sy*c1y + cy*s1y;
            float ncz = cz*c1z - sz*s1z, nsz = sz*c1z + cz*s1z;
            cx=ncx; sx=nsx; cy=ncy; sy=nsy; cz=ncz; sz=nsz;
            const int base = (k-1)*6;
            v[base+0]=cx; v[base+1]=cy; v[base+2]=cz;
            v[base+3]=sx; v[base+4]=sy; v[base+5]=sz;
        }
    }
#pragma unroll
    for (int f = 0; f < 30; ++f) cs[(i << 5) + f] = v[f];
    const int w = tid >> 6;
#pragma unroll
    for (int f = 0; f < 30; ++f) {
        float t = wred64(v[f]);
        if ((tid & 63) == 0) wp[w][f] = t;
    }
    __syncthreads();
    if (tid < 30)
        CSp[(blockIdx.x << 5) + tid] = wp[0][tid] + wp[1][tid] + wp[2][tid] + wp[3][tid];
}

// ---------------------------------------------------------------------------
// k_tp: 256-thread block = 4 independent waves; wave = (i, half); lane walks
// 8 j's of the half. Per-lane accumulators packed __half2.
// M[i][0..9]  : d-power sums (5 up, 5 dn)
// M[i][10..73]: tp1 sums (32 up, 32 dn);  [74..137]: tp2;  [138..201]: tp3
// ---------------------------------------------------------------------------
__global__ __attribute__((amdgpu_flat_work_group_size(256, 256), amdgpu_waves_per_eu(2, 4)))
void k_tp(const float* __restrict__ x,
          const float* __restrict__ Wt0, const float* __restrict__ bt0,
          const float* __restrict__ Wt,  const float* __restrict__ bt,
          float* __restrict__ M)
{
    const int lane = threadIdx.x & 63;
    const int gw   = (blockIdx.x << 2) + (threadIdx.x >> 6);  // 0..2047
    const int i    = gw >> 1;
    const int half = gw & 1;

    const float xi0 = x[3*i+0];
    const float xi1 = x[3*i+1];
    const float xi2 = x[3*i+2];

    __half2 A0h[3], A1h[16], A2h[16], A3h[16];
#pragma unroll
    for (int q = 0; q < 3; ++q)  A0h[q] = __half2(__float2half(0.f), __float2half(0.f));
#pragma unroll
    for (int q = 0; q < 16; ++q) {
        A1h[q] = __half2(__float2half(0.f), __float2half(0.f));
        A2h[q] = __half2(__float2half(0.f), __float2half(0.f));
        A3h[q] = __half2(__float2half(0.f), __float2half(0.f));
    }

#pragma unroll 1
    for (int it = 0; it < 8; ++it) {
        const int j = (half << 9) + (it << 6) + lane;
        const float r0 = xi0 - x[3*j+0];
        const float r1 = xi1 - x[3*j+1];
        const float r2 = xi2 - x[3*j+2];

        // order-1 Fourier (also yields d2 via sin^2(t/2) = (1-cos t)/2)
        float c1x = __cosf(TPILf*r0), s1x = __sinf(TPILf*r0);
        float c1y = __cosf(TPILf*r1), s1y = __sinf(TPILf*r1);
        float c1z = __cosf(TPILf*r2), s1z = __sinf(TPILf*r2);

        float t1[32];
        {
            float d2 = fmaxf(1.5f - 0.5f*(c1x + c1y + c1z), 0.0f);
            float d1 = sqrtf(d2);
            float p0 = d1, p1 = d2, p2 = d2*d1, p3 = d2*d2, p4 = d2*d2*d1;
            A0h[0] = __hadd2(A0h[0], __floats2half2_rn(p0, p1));
            A0h[1] = __hadd2(A0h[1], __floats2half2_rn(p2, p3));
            A0h[2] = __hadd2(A0h[2], __floats2half2_rn(p4, 0.f));
#pragma unroll
            for (int c = 0; c < 32; ++c) {
                float acc = bt0[c];
                acc = fmaf(p0, Wt0[0*32 + c], acc);
                acc = fmaf(p1, Wt0[1*32 + c], acc);
                acc = fmaf(p2, Wt0[2*32 + c], acc);
                acc = fmaf(p3, Wt0[3*32 + c], acc);
                acc = fmaf(p4, Wt0[4*32 + c], acc);
                t1[c] = acc;
            }
        }
        // Fourier features generated incrementally, folded into t1 (never stored)
        {
            float cx=c1x, sx=s1x, cy=c1y, sy=s1y, cz=c1z, sz=s1z;
#pragma unroll
            for (int k = 1; k <= 5; ++k) {
                if (k > 1) {
                    float ncx = cx*c1x - sx*s1x, nsx = sx*c1x + cx*s1x;
                    float ncy = cy*c1y - sy*s1y, nsy = sy*c1y + cy*s1y;
                    float ncz = cz*c1z - sz*s1z, nsz = sz*c1z + cz*s1z;
                    cx=ncx; sx=nsx; cy=ncy; sy=nsy; cz=ncz; sz=nsz;
                }
                const int base = (5 + (k-1)*6) * 32;
#pragma unroll
                for (int c = 0; c < 32; ++c) {
                    float acc = t1[c];
                    acc = fmaf(cx, Wt0[base +   0 + c], acc);
                    acc = fmaf(cy, Wt0[base +  32 + c], acc);
                    acc = fmaf(cz, Wt0[base +  64 + c], acc);
                    acc = fmaf(sx, Wt0[base +  96 + c], acc);
                    acc = fmaf(sy, Wt0[base + 128 + c], acc);
                    acc = fmaf(sz, Wt0[base + 160 + c], acc);
                    t1[c] = acc;
                }
            }
        }
#pragma unroll
        for (int c = 0; c < 32; ++c) t1[c] = sp_f(t1[c]);
#pragma unroll
        for (int q = 0; q < 16; ++q)
            A1h[q] = __hadd2(A1h[q], __floats2half2_rn(t1[2*q], t1[2*q+1]));

        // tp2 = tp1 + softplus(tp1 @ Wt[0] + bt[0])
        float t2[32];
#pragma unroll
        for (int c = 0; c < 32; ++c) t2[c] = bt[c];
#pragma unroll
        for (int k = 0; k < 32; ++k) {
            const float v = t1[k];
#pragma unroll
            for (int c = 0; c < 32; ++c) t2[c] = fmaf(v, Wt[k*32 + c], t2[c]);
        }
#pragma unroll
        for (int c = 0; c < 32; ++c) t2[c] = t1[c] + sp_f(t2[c]);
#pragma unroll
        for (int q = 0; q < 16; ++q)
            A2h[q] = __hadd2(A2h[q], __floats2half2_rn(t2[2*q], t2[2*q+1]));

        // tp3 = tp2 + softplus(tp2 @ Wt[1] + bt[1])  (t3 reuses t1's registers)
        float t3[32];
#pragma unroll
        for (int c = 0; c < 32; ++c) t3[c] = bt[32 + c];
#pragma unroll
        for (int k = 0; k < 32; ++k) {
            const float v = t2[k];
#pragma unroll
            for (int c = 0; c < 32; ++c) t3[c] = fmaf(v, Wt[1024 + k*32 + c], t3[c]);
        }
#pragma unroll
        for (int c = 0; c < 32; ++c) t3[c] = t2[c] + sp_f(t3[c]);
#pragma unroll
        for (int q = 0; q < 16; ++q)
            A3h[q] = __hadd2(A3h[q], __floats2half2_rn(t3[2*q], t3[2*q+1]));
    }

    float* __restrict__ Mi = M + (size_t)i * MSTR;
#pragma unroll
    for (int q = 0; q < 3; ++q) {
        __half2 t = wred64h(A0h[q]);
        if (lane == 0) {
            float2 f = __half22float2(t);
            Mi[half*5 + 2*q] = f.x;
            if (2*q + 1 < 5) Mi[half*5 + 2*q + 1] = f.y;
        }
    }
#pragma unroll
    for (int q = 0; q < 16; ++q) {
        __half2 t = wred64h(A1h[q]);
        if (lane == 0) {
            float2 f = __half22float2(t);
            Mi[10 + half*32 + 2*q] = f.x;
            Mi[10 + half*32 + 2*q + 1] = f.y;
        }
    }
#pragma unroll
    for (int q = 0; q < 16; ++q) {
        __half2 t = wred64h(A2h[q]);
        if (lane == 0) {
            float2 f = __half22float2(t);
            Mi[74 + half*32 + 2*q] = f.x;
            Mi[74 + half*32 + 2*q + 1] = f.y;
        }
    }
#pragma unroll
    for (int q = 0; q < 16; ++q) {
        __half2 t = wred64h(A3h[q]);
        if (lane == 0) {
            float2 f = __half22float2(t);
            Mi[138 + half*32 + 2*q] = f.x;
            Mi[138 + half*32 + 2*q + 1] = f.y;
        }
    }
}

// ---------------------------------------------------------------------------
// k_s1: sp1 = softplus(f0 @ Wsp0 + b); writes SP1 and per-block colsum partials
// ---------------------------------------------------------------------------
__global__ __launch_bounds__(256) void k_s1(
    const float* __restrict__ M, const float* __restrict__ cs,
    const float* __restrict__ CSp,
    const float* __restrict__ W, const float* __restrict__ bv,
    float* __restrict__ SP1, float* __restrict__ P1)
{
    __shared__ float CSsh[2][30];
    __shared__ float feat[4][70];
    __shared__ float red[4][64];
    const int tid = threadIdx.x;
    const int c = tid & 63, g = tid >> 6;
    const int ii = (blockIdx.x << 2) + g;

    if (tid < 60) {
        int hh = tid / 30, f = tid - 30*hh;
        CSsh[hh][f] = CSp[(hh << 6) + f] + CSp[(hh << 6) + 32 + f];
    }
    __syncthreads();
#pragma unroll
    for (int pass = 0; pass < 2; ++pass) {
        const int f = (pass == 0) ? c : 64 + c;
        if (pass == 0 || c < 6) {
            const int sec = (f >= 35) ? 1 : 0;
            const int idx = f - 35*sec;
            float v;
            if (idx < 5) {
                v = M[(size_t)ii * MSTR + sec*5 + idx];
            } else {
                const int gg = idx - 5;
                const int k = gg / 6;
                const int m = gg - 6*k;
                const int dim = (m < 3) ? m : m - 3;
                const float cth = cs[(ii << 5) + k*6 + dim];
                const float sth = cs[(ii << 5) + k*6 + 3 + dim];
                const float Cc  = CSsh[sec][k*6 + dim];
                const float Sc  = CSsh[sec][k*6 + 3 + dim];
                v = (m < 3) ? fmaf(cth, Cc, sth*Sc) : (sth*Cc - cth*Sc);
            }
            feat[g][f] = v * INV512f;
        }
    }
    __syncthreads();
    float acc = bv[c];
#pragma unroll 7
    for (int f = 0; f < 70; ++f)
        acc = fmaf(feat[g][f], W[(9 + f)*64 + c], acc);
    float s = sp_f(acc);
    SP1[(ii << 6) + c] = s;
    red[g][c] = s;
    __syncthreads();
    if (g == 0)
        P1[(blockIdx.x << 6) + c] = red[0][c] + red[1][c] + red[2][c] + red[3][c];
}

// ---------------------------------------------------------------------------
__device__ __forceinline__ float spmid_core(
    int b, int tid,
    const float* __restrict__ SPin, const float* __restrict__ Pin,
    const float* __restrict__ M, int moff,
    const float* __restrict__ W, const float* __restrict__ bv,
    float Sred[2][4][64], float Ssh[2][64], float si[4][64], float featm[4][64])
{
    const int c = tid & 63, g = tid >> 6;
    const int ii = (b << 2) + g;
    float pu = 0.f, pd = 0.f;
#pragma unroll 4
    for (int bb = g; bb < 128; bb += 4) {
        pu += Pin[(bb << 6) + c];
        pd += Pin[((128 + bb) << 6) + c];
    }
    si[g][c]    = SPin[(ii << 6) + c];
    featm[g][c] = M[(size_t)ii * MSTR + moff + c] * INV512f;
    Sred[0][g][c] = pu; Sred[1][g][c] = pd;
    __syncthreads();
    if (g < 2)
        Ssh[g][c] = (Sred[g][0][c] + Sred[g][1][c] + Sred[g][2][c] + Sred[g][3][c]) * INV512f;
    __syncthreads();
    float acc = bv[c];
#pragma unroll 8
    for (int k = 0; k < 64; ++k) acc = fmaf(si[g][k],    W[(k << 6) + c],         acc);
#pragma unroll 8
    for (int k = 0; k < 64; ++k) acc = fmaf(Ssh[0][k],   W[((64 + k) << 6) + c],  acc);
#pragma unroll 8
    for (int k = 0; k < 64; ++k) acc = fmaf(Ssh[1][k],   W[((128 + k) << 6) + c], acc);
#pragma unroll 8
    for (int k = 0; k < 64; ++k) acc = fmaf(featm[g][k], W[((192 + k) << 6) + c], acc);
    return si[g][c] + sp_f(acc);
}

__global__ __launch_bounds__(256) void k_smid(
    const float* __restrict__ SPin, const float* __restrict__ Pin,
    const float* __restrict__ M, int moff,
    const float* __restrict__ W, const float* __restrict__ bv,
    float* __restrict__ SPout, float* __restrict__ Pout)
{
    __shared__ float Sred[2][4][64];
    __shared__ float Ssh[2][64];
    __shared__ float si[4][64];
    __shared__ float featm[4][64];
    const int tid = threadIdx.x;
    float s = spmid_core(blockIdx.x, tid, SPin, Pin, M, moff, W, bv, Sred, Ssh, si, featm);
    const int c = tid & 63, g = tid >> 6;
    SPout[(((blockIdx.x << 2) + g) << 6) + c] = s;
    __syncthreads();
    Sred[0][g][c] = s;
    __syncthreads();
    if (g == 0)
        Pout[(blockIdx.x << 6) + c] = Sred[0][0][c] + Sred[0][1][c] + Sred[0][2][c] + Sred[0][3][c];
}

__global__ __launch_bounds__(256) void k_slast(
    const float* __restrict__ SPin, const float* __restrict__ Pin,
    const float* __restrict__ M, int moff,
    const float* __restrict__ W, const float* __restrict__ bv,
    const float* __restrict__ x,
    const float* __restrict__ Wfin, const float* __restrict__ bfin,
    float* __restrict__ out)
{
    __shared__ float Sred[2][4][64];
    __shared__ float Ssh[2][64];
    __shared__ float si[4][64];
    __shared__ float featm[4][64];
    const int tid = threadIdx.x;
    float s = spmid_core(blockIdx.x, tid, SPin, Pin, M, moff, W, bv, Sred, Ssh, si, featm);
    const int c = tid & 63, g = tid >> 6;
    __syncthreads();
    si[g][c] = s;   // sp4 rows
    __syncthreads();
    if (tid < 12) {
        const int r = tid / 3, d = tid - 3*r;
        const int io = (blockIdx.x << 2) + r;
        float acc = x[3*io + d] + bfin[d];
#pragma unroll 16
        for (int k = 0; k < 64; ++k) acc = fmaf(si[r][k], Wfin[3*k + d], acc);
        out[3*io + d] = acc;
    }
}

extern "C" void kernel_launch(void* const* d_in, const int* in_sizes, int n_in,
                              void* d_out, int out_size, void* d_ws, size_t ws_size,
                              hipStream_t stream)
{
    const float* x    = (const float*)d_in[0];
    const float* Wsp0 = (const float*)d_in[1];
    const float* bsp0 = (const float*)d_in[2];
    const float* Wsp  = (const float*)d_in[3];   // (3, 256, 64)
    const float* bsp  = (const float*)d_in[4];   // (3, 64)
    const float* Wtp0 = (const float*)d_in[5];   // (35, 32)
    const float* btp0 = (const float*)d_in[6];
    const float* Wtp  = (const float*)d_in[7];   // (2, 32, 32)
    const float* btp  = (const float*)d_in[8];   // (2, 32)
    const float* Wfin = (const float*)d_in[9];   // (64, 3)
    const float* bfin = (const float*)d_in[10];
    float* out = (float*)d_out;
    float* ws  = (float*)d_ws;

    // workspace layout (floats); SP3/P3 alias SP1/P1 (dead after S2)
    float* cs  = ws;              // 1024*32
    float* CSp = ws + 32768;      // 4*32
    float* M   = ws + 32896;      // 1024*208
    float* SP1 = ws + 245888;     // 1024*64
    float* SP2 = ws + 311424;     // 1024*64
    float* P1  = ws + 376960;     // 256*64
    float* P2  = ws + 393344;     // 256*64  (end 409728 floats = 1.64 MB)

    k_cs<<<dim3(4),   dim3(256), 0, stream>>>(x, cs, CSp);
    k_tp<<<dim3(512), dim3(256), 0, stream>>>(x, Wtp0, btp0, Wtp, btp, M);
    k_s1<<<dim3(256), dim3(256), 0, stream>>>(M, cs, CSp, Wsp0, bsp0, SP1, P1);
    k_smid<<<dim3(256), dim3(256), 0, stream>>>(SP1, P1, M, 10,  Wsp,         bsp,       SP2, P2);
    k_smid<<<dim3(256), dim3(256), 0, stream>>>(SP2, P2, M, 74,  Wsp + 16384, bsp + 64,  SP1, P1);
    k_slast<<<dim3(256), dim3(256), 0, stream>>>(SP1, P1, M, 138, Wsp + 32768, bsp + 128,
                                                 x, Wfin, bfin, out);
}

// Round 5
// 194.651 us; speedup vs baseline: 2.6447x; 1.8174x over previous
//
#include <hip/hip_runtime.h>
#include <math.h>

// FermiNet_spin: N=1024, DIM=3, NP=5, NF=5, L=10, DEPTH=4, SPSIZE=64, TPSIZE=32
// k_tp v5: lane=column decomposition.
//   Block = (i, eighth) = 128 pairs, 256 threads = 8 half-wave pair-slots.
//   Phase A: lane=pair, compute 35 features -> LDS; d-power sums.
//   Passes L1..L3: lane c owns column c; its column weights in <=35 regs
//   (reloaded per pass), ONE running sum per layer; multipliers broadcast from
//   LDS; t1/t2 staged in LDS (t2 aliases feats). Per-lane live ~90 regs => no
//   spill, no AGPR shuttle (the invariant 350us bottleneck of rounds 1-4).
//   Output: per-eighth sums M8[i][8][104]: [0..5)=d-powers, [5+l*32 .. +32)=layer l.
#define INV512f 0.001953125f
#define TPILf 0.628318530717958648f

__device__ __forceinline__ float sp_f(float v) {
    // softplus, stable: max(v,0) + log1p(exp(-|v|))
    return fmaxf(v, 0.0f) + __logf(1.0f + __expf(-fabsf(v)));
}

__device__ __forceinline__ float wred64(float v) {
    v += __shfl_xor(v, 32, 64);
    v += __shfl_xor(v, 16, 64);
    v += __shfl_xor(v, 8, 64);
    v += __shfl_xor(v, 4, 64);
    v += __shfl_xor(v, 2, 64);
    v += __shfl_xor(v, 1, 64);
    return v;
}

// ---------------------------------------------------------------------------
__global__ __launch_bounds__(256) void k_cs(
    const float* __restrict__ x, float* __restrict__ cs, float* __restrict__ CSp)
{
    __shared__ float wp[4][30];
    const int tid = threadIdx.x;
    const int i = (blockIdx.x << 8) + tid;
    float v[30];
    {
        float a0 = TPILf * x[3*i+0], a1 = TPILf * x[3*i+1], a2 = TPILf * x[3*i+2];
        float c1x = __cosf(a0), s1x = __sinf(a0);
        float c1y = __cosf(a1), s1y = __sinf(a1);
        float c1z = __cosf(a2), s1z = __sinf(a2);
        float cx = c1x, sx = s1x, cy = c1y, sy = s1y, cz = c1z, sz = s1z;
        v[0]=cx; v[1]=cy; v[2]=cz; v[3]=sx; v[4]=sy; v[5]=sz;
#pragma unroll
        for (int k = 2; k <= 5; ++k) {
            float ncx = cx*c1x - sx*s1x, nsx = sx*c1x + cx*s1x;
            float ncy = cy*c1y - sy*s1y, nsy = sy*c1y + cy*s1y;
            float ncz = cz*c1z - sz*s1z, nsz = sz*c1z + cz*s1z;
            cx=ncx; sx=nsx; cy=ncy; sy=nsy; cz=ncz; sz=nsz;
            const int base = (k-1)*6;
            v[base+0]=cx; v[base+1]=cy; v[base+2]=cz;
            v[base+3]=sx; v[base+4]=sy; v[base+5]=sz;
        }
    }
#pragma unroll
    for (int f = 0; f < 30; ++f) cs[(i << 5) + f] = v[f];
    const int w = tid >> 6;
#pragma unroll
    for (int f = 0; f < 30; ++f) {
        float t = wred64(v[f]);
        if ((tid & 63) == 0) wp[w][f] = t;
    }
    __syncthreads();
    if (tid < 30)
        CSp[(blockIdx.x << 5) + tid] = wp[0][tid] + wp[1][tid] + wp[2][tid] + wp[3][tid];
}

// ---------------------------------------------------------------------------
#define FMA4(v4, kb) \
    acc = fmaf((v4).x, Wc[(kb)+0], acc); \
    acc = fmaf((v4).y, Wc[(kb)+1], acc); \
    acc = fmaf((v4).z, Wc[(kb)+2], acc); \
    acc = fmaf((v4).w, Wc[(kb)+3], acc);

__global__ __launch_bounds__(256) void k_tp(
    const float* __restrict__ x,
    const float* __restrict__ Wt0, const float* __restrict__ bt0,
    const float* __restrict__ Wt,  const float* __restrict__ bt,
    float* __restrict__ M8)
{
    __shared__ __align__(16) float LDS[9488];
    float* feats = LDS;            // [128][36]  (18KB)
    float* t1b   = LDS + 4608;     // [128][32]  (16KB)
    float* redp  = LDS + 8704;     // [3][8][32]
    float* rA0   = LDS + 9472;     // [2][5]
    float* t2b   = LDS;            // alias feats (dead after L1 pass)

    const int tid  = threadIdx.x;
    const int i    = blockIdx.x >> 3;
    const int e    = blockIdx.x & 7;
    const int c    = tid & 31;
    const int slot = tid >> 5;

    // ---- Phase A: lane = pair; 35 features -> LDS; d-power per-wave sums
    float p0=0.f, p1=0.f, p2=0.f, p3=0.f, p4=0.f;
    if (tid < 128) {
        const int j = (e << 7) + tid;
        const float r0 = x[3*i+0] - x[3*j+0];
        const float r1 = x[3*i+1] - x[3*j+1];
        const float r2 = x[3*i+2] - x[3*j+2];
        float c1x = __cosf(TPILf*r0), s1x = __sinf(TPILf*r0);
        float c1y = __cosf(TPILf*r1), s1y = __sinf(TPILf*r1);
        float c1z = __cosf(TPILf*r2), s1z = __sinf(TPILf*r2);
        float fb[36];
        // sin^2(t/2) identity: d2 = 1.5 - 0.5*(cos+cos+cos)
        float d2 = fmaxf(1.5f - 0.5f*(c1x + c1y + c1z), 0.0f);
        float d1 = sqrtf(d2);
        fb[0]=d1; fb[1]=d2; fb[2]=d2*d1; fb[3]=d2*d2; fb[4]=d2*d2*d1;
        p0=fb[0]; p1=fb[1]; p2=fb[2]; p3=fb[3]; p4=fb[4];
        float cx=c1x,sx=s1x,cy=c1y,sy=s1y,cz=c1z,sz=s1z;
        fb[5]=cx; fb[6]=cy; fb[7]=cz; fb[8]=sx; fb[9]=sy; fb[10]=sz;
#pragma unroll
        for (int k = 2; k <= 5; ++k) {
            float ncx = cx*c1x - sx*s1x, nsx = sx*c1x + cx*s1x;
            float ncy = cy*c1y - sy*s1y, nsy = sy*c1y + cy*s1y;
            float ncz = cz*c1z - sz*s1z, nsz = sz*c1z + cz*s1z;
            cx=ncx; sx=nsx; cy=ncy; sy=nsy; cz=ncz; sz=nsz;
            const int base = 5 + (k-1)*6;
            fb[base+0]=cx; fb[base+1]=cy; fb[base+2]=cz;
            fb[base+3]=sx; fb[base+4]=sy; fb[base+5]=sz;
        }
        fb[35] = 0.f;
        float4* fv = reinterpret_cast<float4*>(feats + tid*36);
#pragma unroll
        for (int q = 0; q < 9; ++q)
            fv[q] = make_float4(fb[4*q], fb[4*q+1], fb[4*q+2], fb[4*q+3]);
    }
    if (tid < 128) {
        const int w = tid >> 6;
        float s;
        s = wred64(p0); if ((tid & 63) == 0) rA0[w*5+0] = s;
        s = wred64(p1); if ((tid & 63) == 0) rA0[w*5+1] = s;
        s = wred64(p2); if ((tid & 63) == 0) rA0[w*5+2] = s;
        s = wred64(p3); if ((tid & 63) == 0) rA0[w*5+3] = s;
        s = wred64(p4); if ((tid & 63) == 0) rA0[w*5+4] = s;
    }
    __syncthreads();

    const int pbase = slot << 4;
    float A1 = 0.f, A2 = 0.f, A3 = 0.f;
    float Wc[35];

    // ---- L1 pass: t1 = softplus(feats @ Wt0 + bt0)
    {
#pragma unroll
        for (int k = 0; k < 35; ++k) Wc[k] = Wt0[k*32 + c];
        const float bias = bt0[c];
#pragma unroll 1
        for (int t = 0; t < 16; ++t) {
            const int p = pbase + t;
            const float4* fv = reinterpret_cast<const float4*>(feats + p*36);
            float4 f0=fv[0], f1=fv[1], f2=fv[2], f3=fv[3], f4=fv[4],
                   f5=fv[5], f6=fv[6], f7=fv[7], f8=fv[8];
            float acc = bias;
            FMA4(f0,0) FMA4(f1,4) FMA4(f2,8) FMA4(f3,12)
            FMA4(f4,16) FMA4(f5,20) FMA4(f6,24) FMA4(f7,28)
            acc = fmaf(f8.x, Wc[32], acc);
            acc = fmaf(f8.y, Wc[33], acc);
            acc = fmaf(f8.z, Wc[34], acc);
            const float t1v = sp_f(acc);
            A1 += t1v;
            t1b[p*32 + c] = t1v;
        }
    }
    __syncthreads();   // feats area becomes t2b

    // ---- L2 pass: t2 = t1 + softplus(t1 @ Wt[0] + bt[0])
    {
#pragma unroll
        for (int k = 0; k < 32; ++k) Wc[k] = Wt[k*32 + c];
        const float bias = bt[c];
#pragma unroll 1
        for (int t = 0; t < 16; ++t) {
            const int p = pbase + t;
            const float4* tv = reinterpret_cast<const float4*>(t1b + p*32);
            float4 f0=tv[0], f1=tv[1], f2=tv[2], f3=tv[3],
                   f4=tv[4], f5=tv[5], f6=tv[6], f7=tv[7];
            float acc = bias;
            FMA4(f0,0) FMA4(f1,4) FMA4(f2,8) FMA4(f3,12)
            FMA4(f4,16) FMA4(f5,20) FMA4(f6,24) FMA4(f7,28)
            const float prev = t1b[p*32 + c];
            const float t2v = prev + sp_f(acc);
            A2 += t2v;
            t2b[p*32 + c] = t2v;
        }
    }
    // no sync: t2b written/read by the same half-wave (intra-wave ordering)

    // ---- L3 pass: t3 = t2 + softplus(t2 @ Wt[1] + bt[1]); only summed
    {
#pragma unroll
        for (int k = 0; k < 32; ++k) Wc[k] = Wt[1024 + k*32 + c];
        const float bias = bt[32 + c];
#pragma unroll 1
        for (int t = 0; t < 16; ++t) {
            const int p = pbase + t;
            const float4* tv = reinterpret_cast<const float4*>(t2b + p*32);
            float4 f0=tv[0], f1=tv[1], f2=tv[2], f3=tv[3],
                   f4=tv[4], f5=tv[5], f6=tv[6], f7=tv[7];
            float acc = bias;
            FMA4(f0,0) FMA4(f1,4) FMA4(f2,8) FMA4(f3,12)
            FMA4(f4,16) FMA4(f5,20) FMA4(f6,24) FMA4(f7,28)
            const float prev = t2b[p*32 + c];
            A3 += prev + sp_f(acc);
        }
    }

    // ---- reduce the 8 slots, write M8[i][e][104]
    redp[(0*8 + slot)*32 + c] = A1;
    redp[(1*8 + slot)*32 + c] = A2;
    redp[(2*8 + slot)*32 + c] = A3;
    __syncthreads();
    float* M8e = M8 + ((size_t)i*8 + e)*104;
    if (tid < 96) {
        const int l = tid >> 5, cc = tid & 31;
        const float* rp = redp + l*256 + cc;
        M8e[5 + l*32 + cc] = rp[0]+rp[32]+rp[64]+rp[96]+rp[128]+rp[160]+rp[192]+rp[224];
    }
    if (tid < 5)
        M8e[tid] = rA0[tid] + rA0[5 + tid];
}

// ---------------------------------------------------------------------------
// k_s1: sp1 = softplus(f0 @ Wsp0 + b); Fourier tp-sums reconstructed from cs/CSp
// ---------------------------------------------------------------------------
__global__ __launch_bounds__(256) void k_s1(
    const float* __restrict__ M8, const float* __restrict__ cs,
    const float* __restrict__ CSp,
    const float* __restrict__ W, const float* __restrict__ bv,
    float* __restrict__ SP1, float* __restrict__ P1)
{
    __shared__ float CSsh[2][30];
    __shared__ float feat[4][70];
    __shared__ float red[4][64];
    const int tid = threadIdx.x;
    const int c = tid & 63, g = tid >> 6;
    const int ii = (blockIdx.x << 2) + g;

    if (tid < 60) {
        int hh = tid / 30, f = tid - 30*hh;
        CSsh[hh][f] = CSp[(hh << 6) + f] + CSp[(hh << 6) + 32 + f];
    }
    __syncthreads();
#pragma unroll
    for (int pass = 0; pass < 2; ++pass) {
        const int f = (pass == 0) ? c : 64 + c;
        if (pass == 0 || c < 6) {
            const int sec = (f >= 35) ? 1 : 0;
            const int idx = f - 35*sec;
            float v;
            if (idx < 5) {
                const float* mp = M8 + ((size_t)ii*8 + sec*4)*104 + idx;
                v = mp[0] + mp[104] + mp[208] + mp[312];
            } else {
                const int gg = idx - 5;
                const int k = gg / 6;
                const int m = gg - 6*k;
                const int dim = (m < 3) ? m : m - 3;
                const float cth = cs[(ii << 5) + k*6 + dim];
                const float sth = cs[(ii << 5) + k*6 + 3 + dim];
                const float Cc  = CSsh[sec][k*6 + dim];
                const float Sc  = CSsh[sec][k*6 + 3 + dim];
                v = (m < 3) ? fmaf(cth, Cc, sth*Sc) : (sth*Cc - cth*Sc);
            }
            feat[g][f] = v * INV512f;
        }
    }
    __syncthreads();
    float acc = bv[c];
#pragma unroll 7
    for (int f = 0; f < 70; ++f)
        acc = fmaf(feat[g][f], W[(9 + f)*64 + c], acc);
    float s = sp_f(acc);
    SP1[(ii << 6) + c] = s;
    red[g][c] = s;
    __syncthreads();
    if (g == 0)
        P1[(blockIdx.x << 6) + c] = red[0][c] + red[1][c] + red[2][c] + red[3][c];
}

// ---------------------------------------------------------------------------
__device__ __forceinline__ float spmid_core(
    int b, int tid,
    const float* __restrict__ SPin, const float* __restrict__ Pin,
    const float* __restrict__ M8, int loff,
    const float* __restrict__ W, const float* __restrict__ bv,
    float Sred[2][4][64], float Ssh[2][64], float si[4][64], float featm[4][64])
{
    const int c = tid & 63, g = tid >> 6;
    const int ii = (b << 2) + g;
    float pu = 0.f, pd = 0.f;
#pragma unroll 4
    for (int bb = g; bb < 128; bb += 4) {
        pu += Pin[(bb << 6) + c];
        pd += Pin[((128 + bb) << 6) + c];
    }
    si[g][c] = SPin[(ii << 6) + c];
    {
        const int h = c >> 5, cc = c & 31;
        const float* mp = M8 + ((size_t)ii*8 + h*4)*104 + loff + cc;
        featm[g][c] = (mp[0] + mp[104] + mp[208] + mp[312]) * INV512f;
    }
    Sred[0][g][c] = pu; Sred[1][g][c] = pd;
    __syncthreads();
    if (g < 2)
        Ssh[g][c] = (Sred[g][0][c] + Sred[g][1][c] + Sred[g][2][c] + Sred[g][3][c]) * INV512f;
    __syncthreads();
    float acc = bv[c];
#pragma unroll 8
    for (int k = 0; k < 64; ++k) acc = fmaf(si[g][k],    W[(k << 6) + c],         acc);
#pragma unroll 8
    for (int k = 0; k < 64; ++k) acc = fmaf(Ssh[0][k],   W[((64 + k) << 6) + c],  acc);
#pragma unroll 8
    for (int k = 0; k < 64; ++k) acc = fmaf(Ssh[1][k],   W[((128 + k) << 6) + c], acc);
#pragma unroll 8
    for (int k = 0; k < 64; ++k) acc = fmaf(featm[g][k], W[((192 + k) << 6) + c], acc);
    return si[g][c] + sp_f(acc);
}

__global__ __launch_bounds__(256) void k_smid(
    const float* __restrict__ SPin, const float* __restrict__ Pin,
    const float* __restrict__ M8, int loff,
    const float* __restrict__ W, const float* __restrict__ bv,
    float* __restrict__ SPout, float* __restrict__ Pout)
{
    __shared__ float Sred[2][4][64];
    __shared__ float Ssh[2][64];
    __shared__ float si[4][64];
    __shared__ float featm[4][64];
    const int tid = threadIdx.x;
    float s = spmid_core(blockIdx.x, tid, SPin, Pin, M8, loff, W, bv, Sred, Ssh, si, featm);
    const int c = tid & 63, g = tid >> 6;
    SPout[(((blockIdx.x << 2) + g) << 6) + c] = s;
    __syncthreads();
    Sred[0][g][c] = s;
    __syncthreads();
    if (g == 0)
        Pout[(blockIdx.x << 6) + c] = Sred[0][0][c] + Sred[0][1][c] + Sred[0][2][c] + Sred[0][3][c];
}

__global__ __launch_bounds__(256) void k_slast(
    const float* __restrict__ SPin, const float* __restrict__ Pin,
    const float* __restrict__ M8, int loff,
    const float* __restrict__ W, const float* __restrict__ bv,
    const float* __restrict__ x,
    const float* __restrict__ Wfin, const float* __restrict__ bfin,
    float* __restrict__ out)
{
    __shared__ float Sred[2][4][64];
    __shared__ float Ssh[2][64];
    __shared__ float si[4][64];
    __shared__ float featm[4][64];
    const int tid = threadIdx.x;
    float s = spmid_core(blockIdx.x, tid, SPin, Pin, M8, loff, W, bv, Sred, Ssh, si, featm);
    const int c = tid & 63, g = tid >> 6;
    __syncthreads();
    si[g][c] = s;   // sp4 rows
    __syncthreads();
    if (tid < 12) {
        const int r = tid / 3, d = tid - 3*r;
        const int io = (blockIdx.x << 2) + r;
        float acc = x[3*io + d] + bfin[d];
#pragma unroll 16
        for (int k = 0; k < 64; ++k) acc = fmaf(si[r][k], Wfin[3*k + d], acc);
        out[3*io + d] = acc;
    }
}

extern "C" void kernel_launch(void* const* d_in, const int* in_sizes, int n_in,
                              void* d_out, int out_size, void* d_ws, size_t ws_size,
                              hipStream_t stream)
{
    const float* x    = (const float*)d_in[0];
    const float* Wsp0 = (const float*)d_in[1];
    const float* bsp0 = (const float*)d_in[2];
    const float* Wsp  = (const float*)d_in[3];   // (3, 256, 64)
    const float* bsp  = (const float*)d_in[4];   // (3, 64)
    const float* Wtp0 = (const float*)d_in[5];   // (35, 32)
    const float* btp0 = (const float*)d_in[6];
    const float* Wtp  = (const float*)d_in[7];   // (2, 32, 32)
    const float* btp  = (const float*)d_in[8];   // (2, 32)
    const float* Wfin = (const float*)d_in[9];   // (64, 3)
    const float* bfin = (const float*)d_in[10];
    float* out = (float*)d_out;
    float* ws  = (float*)d_ws;

    // workspace layout (floats)
    float* cs  = ws;               // 1024*32      = 32768
    float* CSp = ws + 32768;       // 4*32         = 128
    float* M8  = ws + 32896;       // 1024*8*104   = 851968
    float* SP1 = ws + 884864;      // 1024*64
    float* SP2 = ws + 950400;      // 1024*64
    float* P1  = ws + 1015936;     // 256*64
    float* P2  = ws + 1032320;     // 256*64   (end 1048704 floats ~= 4.2 MB)

    k_cs<<<dim3(4),    dim3(256), 0, stream>>>(x, cs, CSp);
    k_tp<<<dim3(8192), dim3(256), 0, stream>>>(x, Wtp0, btp0, Wtp, btp, M8);
    k_s1<<<dim3(256),  dim3(256), 0, stream>>>(M8, cs, CSp, Wsp0, bsp0, SP1, P1);
    k_smid<<<dim3(256), dim3(256), 0, stream>>>(SP1, P1, M8, 5,  Wsp,         bsp,       SP2, P2);
    k_smid<<<dim3(256), dim3(256), 0, stream>>>(SP2, P2, M8, 37, Wsp + 16384, bsp + 64,  SP1, P1);
    k_slast<<<dim3(256), dim3(256), 0, stream>>>(SP1, P1, M8, 69, Wsp + 32768, bsp + 128,
                                                 x, Wfin, bfin, out);
}

// Round 7
// 120.204 us; speedup vs baseline: 4.2826x; 1.6193x over previous
//
#include <hip/hip_runtime.h>
#include <math.h>

// FermiNet_spin: N=1024, DIM=3, NP=5, NF=5, L=10, DEPTH=4, SPSIZE=64, TPSIZE=32
// k_tp v6b: MFMA pair-stream (round-6 fix: cvt_pkrtz bit_cast).
//   Block = (i, eighth) = 128 pairs, 4 waves; wave owns 32 pairs (2 groups of 16).
//   Phase A: lane=pair computes 35 features -> LDS rows as f16 (stride 176B,
//            K-pad 35..63 zeroed); d-power sums via shuffle.
//   Layers: D[m=col][n=pair] = W^T x feats^T on mfma_f32_16x16x32_f16.
//     A-frag = weights (built once from global, K>=Klim zeroed in A so LDS
//     garbage multiplies 0), B-frag = one ds_read_b128 per pair row.
//     softplus/bias/skip in f32 VALU; t1/t2 stay in-lane (D col=lane&15=pair,
//     row=(lane>>4)*4+q=col). t rows per-wave-private (same-wave LDS order).
//   Column sums: 2-step shfl_xor (pairs) + LDS tree (waves/groups).
//   Output M8[i][8][104] unchanged -> phase B identical to round 5.
#define INV512f 0.001953125f
#define TPILf 0.628318530717958648f

typedef __attribute__((ext_vector_type(8))) _Float16 f16x8;
typedef __attribute__((ext_vector_type(4))) float f32x4;

__device__ __forceinline__ float sp_f(float v) {
    // softplus, stable: max(v,0) + log1p(exp(-|v|))
    return fmaxf(v, 0.0f) + __logf(1.0f + __expf(-fabsf(v)));
}

__device__ __forceinline__ float wred64(float v) {
    v += __shfl_xor(v, 32, 64);
    v += __shfl_xor(v, 16, 64);
    v += __shfl_xor(v, 8, 64);
    v += __shfl_xor(v, 4, 64);
    v += __shfl_xor(v, 2, 64);
    v += __shfl_xor(v, 1, 64);
    return v;
}

__device__ __forceinline__ unsigned pkh(float a, float b) {
    return __builtin_bit_cast(unsigned, __builtin_amdgcn_cvt_pkrtz(a, b));
}

// A-frag: lane holds A[m=c][k=kbase+e] = W[k][c]; zeros for k>=Klim
__device__ __forceinline__ f16x8 wfrag(const float* __restrict__ W,
                                       int kbase, int c, int Klim) {
    f16x8 r;
#pragma unroll
    for (int e = 0; e < 8; ++e) {
        const int k = kbase + e;
        const float v = (k < Klim) ? W[k * 32 + c] : 0.f;
        r[e] = (_Float16)v;
    }
    return r;
}

// ---------------------------------------------------------------------------
__global__ __launch_bounds__(256) void k_cs(
    const float* __restrict__ x, float* __restrict__ cs, float* __restrict__ CSp)
{
    __shared__ float wp[4][30];
    const int tid = threadIdx.x;
    const int i = (blockIdx.x << 8) + tid;
    float v[30];
    {
        float a0 = TPILf * x[3*i+0], a1 = TPILf * x[3*i+1], a2 = TPILf * x[3*i+2];
        float c1x = __cosf(a0), s1x = __sinf(a0);
        float c1y = __cosf(a1), s1y = __sinf(a1);
        float c1z = __cosf(a2), s1z = __sinf(a2);
        float cx = c1x, sx = s1x, cy = c1y, sy = s1y, cz = c1z, sz = s1z;
        v[0]=cx; v[1]=cy; v[2]=cz; v[3]=sx; v[4]=sy; v[5]=sz;
#pragma unroll
        for (int k = 2; k <= 5; ++k) {
            float ncx = cx*c1x - sx*s1x, nsx = sx*c1x + cx*s1x;
            float ncy = cy*c1y - sy*s1y, nsy = sy*c1y + cy*s1y;
            float ncz = cz*c1z - sz*s1z, nsz = sz*c1z + cz*s1z;
            cx=ncx; sx=nsx; cy=ncy; sy=nsy; cz=ncz; sz=nsz;
            const int base = (k-1)*6;
            v[base+0]=cx; v[base+1]=cy; v[base+2]=cz;
            v[base+3]=sx; v[base+4]=sy; v[base+5]=sz;
        }
    }
#pragma unroll
    for (int f = 0; f < 30; ++f) cs[(i << 5) + f] = v[f];
    const int w = tid >> 6;
#pragma unroll
    for (int f = 0; f < 30; ++f) {
        float t = wred64(v[f]);
        if ((tid & 63) == 0) wp[w][f] = t;
    }
    __syncthreads();
    if (tid < 30)
        CSp[(blockIdx.x << 5) + tid] = wp[0][tid] + wp[1][tid] + wp[2][tid] + wp[3][tid];
}

// ---------------------------------------------------------------------------
// LDS map (bytes):
//   feats : [128 pairs][176]  f16 rows (halves 0..34 data, 35..63 zero) @ 0
//   tbuf  : [4 waves][16][80] f16 t rows                                @ 22528
//   redp3 : [3 layers][4 waves][4 grp][32 c] f32                        @ 27648
//   rA0   : [2][5] f32                                                  @ 33792
// ---------------------------------------------------------------------------
__global__ __launch_bounds__(256) void k_tp(
    const float* __restrict__ x,
    const float* __restrict__ Wt0, const float* __restrict__ bt0,
    const float* __restrict__ Wt,  const float* __restrict__ bt,
    float* __restrict__ M8)
{
    __shared__ __align__(16) float LDS[8460];
    char*  LDSC  = (char*)LDS;
    float* redp3 = LDS + 6912;
    float* rA0   = LDS + 8448;

    const int tid = threadIdx.x;
    const int i   = blockIdx.x >> 3;
    const int e8  = blockIdx.x & 7;

    // ---- Phase A: lane = pair; 35 f16 features -> LDS; d-power sums
    if (tid < 128) {
        const int j = (e8 << 7) + tid;
        const float r0 = x[3*i+0] - x[3*j+0];
        const float r1 = x[3*i+1] - x[3*j+1];
        const float r2 = x[3*i+2] - x[3*j+2];
        float c1x = __cosf(TPILf*r0), s1x = __sinf(TPILf*r0);
        float c1y = __cosf(TPILf*r1), s1y = __sinf(TPILf*r1);
        float c1z = __cosf(TPILf*r2), s1z = __sinf(TPILf*r2);
        float fb[35];
        // sin^2(t/2) identity: d2 = 1.5 - 0.5*(cos+cos+cos)
        float d2 = fmaxf(1.5f - 0.5f*(c1x + c1y + c1z), 0.0f);
        float d1 = sqrtf(d2);
        fb[0]=d1; fb[1]=d2; fb[2]=d2*d1; fb[3]=d2*d2; fb[4]=d2*d2*d1;
        float cx=c1x,sx=s1x,cy=c1y,sy=s1y,cz=c1z,sz=s1z;
        fb[5]=cx; fb[6]=cy; fb[7]=cz; fb[8]=sx; fb[9]=sy; fb[10]=sz;
#pragma unroll
        for (int k = 2; k <= 5; ++k) {
            float ncx = cx*c1x - sx*s1x, nsx = sx*c1x + cx*s1x;
            float ncy = cy*c1y - sy*s1y, nsy = sy*c1y + cy*s1y;
            float ncz = cz*c1z - sz*s1z, nsz = sz*c1z + cz*s1z;
            cx=ncx; sx=nsx; cy=ncy; sy=nsy; cz=ncz; sz=nsz;
            const int base = 5 + (k-1)*6;
            fb[base+0]=cx; fb[base+1]=cy; fb[base+2]=cz;
            fb[base+3]=sx; fb[base+4]=sy; fb[base+5]=sz;
        }
        unsigned wds[18];
#pragma unroll
        for (int q2 = 0; q2 < 17; ++q2) wds[q2] = pkh(fb[2*q2], fb[2*q2+1]);
        wds[17] = pkh(fb[34], 0.f);
        uint4* fr = (uint4*)(LDSC + tid*176);
        fr[0] = make_uint4(wds[0], wds[1], wds[2], wds[3]);
        fr[1] = make_uint4(wds[4], wds[5], wds[6], wds[7]);
        fr[2] = make_uint4(wds[8], wds[9], wds[10], wds[11]);
        fr[3] = make_uint4(wds[12], wds[13], wds[14], wds[15]);
        fr[4] = make_uint4(wds[16], wds[17], 0u, 0u);
        fr[5] = make_uint4(0u, 0u, 0u, 0u);
        fr[6] = make_uint4(0u, 0u, 0u, 0u);
        fr[7] = make_uint4(0u, 0u, 0u, 0u);
        // d-power sums (per 64-pair wave)
        const int w2 = tid >> 6;
        float s;
        s = wred64(fb[0]); if ((tid & 63) == 0) rA0[w2*5+0] = s;
        s = wred64(fb[1]); if ((tid & 63) == 0) rA0[w2*5+1] = s;
        s = wred64(fb[2]); if ((tid & 63) == 0) rA0[w2*5+2] = s;
        s = wred64(fb[3]); if ((tid & 63) == 0) rA0[w2*5+3] = s;
        s = wred64(fb[4]); if ((tid & 63) == 0) rA0[w2*5+4] = s;
    }
    __syncthreads();

    const int l  = tid & 63;
    const int wv = tid >> 6;
    const int lm = l & 15;    // pair-in-group (n) / col-within-half for A
    const int lq = l >> 4;    // k-chunk

    // weight A-frags (global, L2-cached; built once)
    f16x8 a1a0 = wfrag(Wt0,        lq*8,      lm,      35);
    f16x8 a1b0 = wfrag(Wt0,        lq*8,      lm + 16, 35);
    f16x8 a1a1 = wfrag(Wt0,        32 + lq*8, lm,      35);
    f16x8 a1b1 = wfrag(Wt0,        32 + lq*8, lm + 16, 35);
    f16x8 a2a  = wfrag(Wt,         lq*8,      lm,      32);
    f16x8 a2b  = wfrag(Wt,         lq*8,      lm + 16, 32);
    f16x8 a3a  = wfrag(Wt + 1024,  lq*8,      lm,      32);
    f16x8 a3b  = wfrag(Wt + 1024,  lq*8,      lm + 16, 32);

    float b1a[4], b1b[4], b2a[4], b2b[4], b3a[4], b3b[4];
    {
        float4 t;
        t = *(const float4*)&bt0[lq*4];      b1a[0]=t.x; b1a[1]=t.y; b1a[2]=t.z; b1a[3]=t.w;
        t = *(const float4*)&bt0[16+lq*4];   b1b[0]=t.x; b1b[1]=t.y; b1b[2]=t.z; b1b[3]=t.w;
        t = *(const float4*)&bt[lq*4];       b2a[0]=t.x; b2a[1]=t.y; b2a[2]=t.z; b2a[3]=t.w;
        t = *(const float4*)&bt[16+lq*4];    b2b[0]=t.x; b2b[1]=t.y; b2b[2]=t.z; b2b[3]=t.w;
        t = *(const float4*)&bt[32+lq*4];    b3a[0]=t.x; b3a[1]=t.y; b3a[2]=t.z; b3a[3]=t.w;
        t = *(const float4*)&bt[48+lq*4];    b3b[0]=t.x; b3b[1]=t.y; b3b[2]=t.z; b3b[3]=t.w;
    }

    float A1[8], A2[8], A3[8];
#pragma unroll
    for (int q = 0; q < 8; ++q) { A1[q]=0.f; A2[q]=0.f; A3[q]=0.f; }

    char* tr = LDSC + 22528 + ((wv << 4) + lm) * 80;

#pragma unroll 1
    for (int g = 0; g < 2; ++g) {
        const int prow = (wv << 5) + (g << 4) + lm;
        const char* fr = LDSC + prow * 176;
        f16x8 bf0 = *(const f16x8*)(fr + lq*16);        // feats k 0..31
        f16x8 bf1 = *(const f16x8*)(fr + 64 + lq*16);   // feats k 32..63 (pad 0)

        // L1: D = W1^T(35x32, K-padded) x feats^T
        f32x4 d0a = {0.f,0.f,0.f,0.f}, d0b = {0.f,0.f,0.f,0.f};
        d0a = __builtin_amdgcn_mfma_f32_16x16x32_f16(a1a0, bf0, d0a, 0, 0, 0);
        d0a = __builtin_amdgcn_mfma_f32_16x16x32_f16(a1a1, bf1, d0a, 0, 0, 0);
        d0b = __builtin_amdgcn_mfma_f32_16x16x32_f16(a1b0, bf0, d0b, 0, 0, 0);
        d0b = __builtin_amdgcn_mfma_f32_16x16x32_f16(a1b1, bf1, d0b, 0, 0, 0);

        float t1v[8];
#pragma unroll
        for (int q = 0; q < 4; ++q) {
            t1v[q]     = sp_f(d0a[q] + b1a[q]);  A1[q]     += t1v[q];
            t1v[4+q]   = sp_f(d0b[q] + b1b[q]);  A1[4+q]   += t1v[4+q];
        }
        *(uint2*)(tr + lq*8)      = make_uint2(pkh(t1v[0], t1v[1]), pkh(t1v[2], t1v[3]));
        *(uint2*)(tr + 32 + lq*8) = make_uint2(pkh(t1v[4], t1v[5]), pkh(t1v[6], t1v[7]));
        asm volatile("" ::: "memory");

        // L2
        f16x8 btf = *(const f16x8*)(tr + lq*16);
        f32x4 d2a_ = {0.f,0.f,0.f,0.f}, d2b_ = {0.f,0.f,0.f,0.f};
        d2a_ = __builtin_amdgcn_mfma_f32_16x16x32_f16(a2a, btf, d2a_, 0, 0, 0);
        d2b_ = __builtin_amdgcn_mfma_f32_16x16x32_f16(a2b, btf, d2b_, 0, 0, 0);
        float t2v[8];
#pragma unroll
        for (int q = 0; q < 4; ++q) {
            t2v[q]   = t1v[q]   + sp_f(d2a_[q] + b2a[q]);  A2[q]   += t2v[q];
            t2v[4+q] = t1v[4+q] + sp_f(d2b_[q] + b2b[q]);  A2[4+q] += t2v[4+q];
        }
        *(uint2*)(tr + lq*8)      = make_uint2(pkh(t2v[0], t2v[1]), pkh(t2v[2], t2v[3]));
        *(uint2*)(tr + 32 + lq*8) = make_uint2(pkh(t2v[4], t2v[5]), pkh(t2v[6], t2v[7]));
        asm volatile("" ::: "memory");

        // L3 (sums only)
        f16x8 btg = *(const f16x8*)(tr + lq*16);
        f32x4 d3a_ = {0.f,0.f,0.f,0.f}, d3b_ = {0.f,0.f,0.f,0.f};
        d3a_ = __builtin_amdgcn_mfma_f32_16x16x32_f16(a3a, btg, d3a_, 0, 0, 0);
        d3b_ = __builtin_amdgcn_mfma_f32_16x16x32_f16(a3b, btg, d3b_, 0, 0, 0);
#pragma unroll
        for (int q = 0; q < 4; ++q) {
            A3[q]   += t2v[q]   + sp_f(d3a_[q] + b3a[q]);
            A3[4+q] += t2v[4+q] + sp_f(d3b_[q] + b3b[q]);
        }
    }

    // ---- reduce over pairs: 2-step butterfly (lm bits 0,1), then LDS tree
#pragma unroll
    for (int q = 0; q < 8; ++q) {
        A1[q] += __shfl_xor(A1[q], 1, 64);  A1[q] += __shfl_xor(A1[q], 2, 64);
        A2[q] += __shfl_xor(A2[q], 1, 64);  A2[q] += __shfl_xor(A2[q], 2, 64);
        A3[q] += __shfl_xor(A3[q], 1, 64);  A3[q] += __shfl_xor(A3[q], 2, 64);
    }
    if ((lm & 3) == 0) {
        const int grp = lm >> 2;
        const int base0 = ((0*4 + wv)*4 + grp)*32;
        const int base1 = ((1*4 + wv)*4 + grp)*32;
        const int base2 = ((2*4 + wv)*4 + grp)*32;
        *(float4*)&redp3[base0 + lq*4]      = make_float4(A1[0], A1[1], A1[2], A1[3]);
        *(float4*)&redp3[base0 + 16 + lq*4] = make_float4(A1[4], A1[5], A1[6], A1[7]);
        *(float4*)&redp3[base1 + lq*4]      = make_float4(A2[0], A2[1], A2[2], A2[3]);
        *(float4*)&redp3[base1 + 16 + lq*4] = make_float4(A2[4], A2[5], A2[6], A2[7]);
        *(float4*)&redp3[base2 + lq*4]      = make_float4(A3[0], A3[1], A3[2], A3[3]);
        *(float4*)&redp3[base2 + 16 + lq*4] = make_float4(A3[4], A3[5], A3[6], A3[7]);
    }
    __syncthreads();

    float* M8e = M8 + ((size_t)i*8 + e8)*104;
    if (tid < 96) {
        const int layer = tid >> 5, c = tid & 31;
        float s = 0.f;
#pragma unroll
        for (int w2 = 0; w2 < 16; ++w2)
            s += redp3[(layer*16 + w2)*32 + c];
        M8e[5 + layer*32 + c] = s;
    }
    if (tid < 5)
        M8e[tid] = rA0[tid] + rA0[5 + tid];
}

// ---------------------------------------------------------------------------
// k_s1: sp1 = softplus(f0 @ Wsp0 + b); Fourier tp-sums reconstructed from cs/CSp
// ---------------------------------------------------------------------------
__global__ __launch_bounds__(256) void k_s1(
    const float* __restrict__ M8, const float* __restrict__ cs,
    const float* __restrict__ CSp,
    const float* __restrict__ W, const float* __restrict__ bv,
    float* __restrict__ SP1, float* __restrict__ P1)
{
    __shared__ float CSsh[2][30];
    __shared__ float feat[4][70];
    __shared__ float red[4][64];
    const int tid = threadIdx.x;
    const int c = tid & 63, g = tid >> 6;
    const int ii = (blockIdx.x << 2) + g;

    if (tid < 60) {
        int hh = tid / 30, f = tid - 30*hh;
        CSsh[hh][f] = CSp[(hh << 6) + f] + CSp[(hh << 6) + 32 + f];
    }
    __syncthreads();
#pragma unroll
    for (int pass = 0; pass < 2; ++pass) {
        const int f = (pass == 0) ? c : 64 + c;
        if (pass == 0 || c < 6) {
            const int sec = (f >= 35) ? 1 : 0;
            const int idx = f - 35*sec;
            float v;
            if (idx < 5) {
                const float* mp = M8 + ((size_t)ii*8 + sec*4)*104 + idx;
                v = mp[0] + mp[104] + mp[208] + mp[312];
            } else {
                const int gg = idx - 5;
                const int k = gg / 6;
                const int m = gg - 6*k;
                const int dim = (m < 3) ? m : m - 3;
                const float cth = cs[(ii << 5) + k*6 + dim];
                const float sth = cs[(ii << 5) + k*6 + 3 + dim];
                const float Cc  = CSsh[sec][k*6 + dim];
                const float Sc  = CSsh[sec][k*6 + 3 + dim];
                v = (m < 3) ? fmaf(cth, Cc, sth*Sc) : (sth*Cc - cth*Sc);
            }
            feat[g][f] = v * INV512f;
        }
    }
    __syncthreads();
    float acc = bv[c];
#pragma unroll 7
    for (int f = 0; f < 70; ++f)
        acc = fmaf(feat[g][f], W[(9 + f)*64 + c], acc);
    float s = sp_f(acc);
    SP1[(ii << 6) + c] = s;
    red[g][c] = s;
    __syncthreads();
    if (g == 0)
        P1[(blockIdx.x << 6) + c] = red[0][c] + red[1][c] + red[2][c] + red[3][c];
}

// ---------------------------------------------------------------------------
__device__ __forceinline__ float spmid_core(
    int b, int tid,
    const float* __restrict__ SPin, const float* __restrict__ Pin,
    const float* __restrict__ M8, int loff,
    const float* __restrict__ W, const float* __restrict__ bv,
    float Sred[2][4][64], float Ssh[2][64], float si[4][64], float featm[4][64])
{
    const int c = tid & 63, g = tid >> 6;
    const int ii = (b << 2) + g;
    float pu = 0.f, pd = 0.f;
#pragma unroll 4
    for (int bb = g; bb < 128; bb += 4) {
        pu += Pin[(bb << 6) + c];
        pd += Pin[((128 + bb) << 6) + c];
    }
    si[g][c] = SPin[(ii << 6) + c];
    {
        const int h = c >> 5, cc = c & 31;
        const float* mp = M8 + ((size_t)ii*8 + h*4)*104 + loff + cc;
        featm[g][c] = (mp[0] + mp[104] + mp[208] + mp[312]) * INV512f;
    }
    Sred[0][g][c] = pu; Sred[1][g][c] = pd;
    __syncthreads();
    if (g < 2)
        Ssh[g][c] = (Sred[g][0][c] + Sred[g][1][c] + Sred[g][2][c] + Sred[g][3][c]) * INV512f;
    __syncthreads();
    float acc = bv[c];
#pragma unroll 8
    for (int k = 0; k < 64; ++k) acc = fmaf(si[g][k],    W[(k << 6) + c],         acc);
#pragma unroll 8
    for (int k = 0; k < 64; ++k) acc = fmaf(Ssh[0][k],   W[((64 + k) << 6) + c],  acc);
#pragma unroll 8
    for (int k = 0; k < 64; ++k) acc = fmaf(Ssh[1][k],   W[((128 + k) << 6) + c], acc);
#pragma unroll 8
    for (int k = 0; k < 64; ++k) acc = fmaf(featm[g][k], W[((192 + k) << 6) + c], acc);
    return si[g][c] + sp_f(acc);
}

__global__ __launch_bounds__(256) void k_smid(
    const float* __restrict__ SPin, const float* __restrict__ Pin,
    const float* __restrict__ M8, int loff,
    const float* __restrict__ W, const float* __restrict__ bv,
    float* __restrict__ SPout, float* __restrict__ Pout)
{
    __shared__ float Sred[2][4][64];
    __shared__ float Ssh[2][64];
    __shared__ float si[4][64];
    __shared__ float featm[4][64];
    const int tid = threadIdx.x;
    float s = spmid_core(blockIdx.x, tid, SPin, Pin, M8, loff, W, bv, Sred, Ssh, si, featm);
    const int c = tid & 63, g = tid >> 6;
    SPout[(((blockIdx.x << 2) + g) << 6) + c] = s;
    __syncthreads();
    Sred[0][g][c] = s;
    __syncthreads();
    if (g == 0)
        Pout[(blockIdx.x << 6) + c] = Sred[0][0][c] + Sred[0][1][c] + Sred[0][2][c] + Sred[0][3][c];
}

__global__ __launch_bounds__(256) void k_slast(
    const float* __restrict__ SPin, const float* __restrict__ Pin,
    const float* __restrict__ M8, int loff,
    const float* __restrict__ W, const float* __restrict__ bv,
    const float* __restrict__ x,
    const float* __restrict__ Wfin, const float* __restrict__ bfin,
    float* __restrict__ out)
{
    __shared__ float Sred[2][4][64];
    __shared__ float Ssh[2][64];
    __shared__ float si[4][64];
    __shared__ float featm[4][64];
    const int tid = threadIdx.x;
    float s = spmid_core(blockIdx.x, tid, SPin, Pin, M8, loff, W, bv, Sred, Ssh, si, featm);
    const int c = tid & 63, g = tid >> 6;
    __syncthreads();
    si[g][c] = s;   // sp4 rows
    __syncthreads();
    if (tid < 12) {
        const int r = tid / 3, d = tid - 3*r;
        const int io = (blockIdx.x << 2) + r;
        float acc = x[3*io + d] + bfin[d];
#pragma unroll 16
        for (int k = 0; k < 64; ++k) acc = fmaf(si[r][k], Wfin[3*k + d], acc);
        out[3*io + d] = acc;
    }
}

extern "C" void kernel_launch(void* const* d_in, const int* in_sizes, int n_in,
                              void* d_out, int out_size, void* d_ws, size_t ws_size,
                              hipStream_t stream)
{
    const float* x    = (const float*)d_in[0];
    const float* Wsp0 = (const float*)d_in[1];
    const float* bsp0 = (const float*)d_in[2];
    const float* Wsp  = (const float*)d_in[3];   // (3, 256, 64)
    const float* bsp  = (const float*)d_in[4];   // (3, 64)
    const float* Wtp0 = (const float*)d_in[5];   // (35, 32)
    const float* btp0 = (const float*)d_in[6];
    const float* Wtp  = (const float*)d_in[7];   // (2, 32, 32)
    const float* btp  = (const float*)d_in[8];   // (2, 32)
    const float* Wfin = (const float*)d_in[9];   // (64, 3)
    const float* bfin = (const float*)d_in[10];
    float* out = (float*)d_out;
    float* ws  = (float*)d_ws;

    // workspace layout (floats)
    float* cs  = ws;               // 1024*32      = 32768
    float* CSp = ws + 32768;       // 4*32         = 128
    float* M8  = ws + 32896;       // 1024*8*104   = 851968
    float* SP1 = ws + 884864;      // 1024*64
    float* SP2 = ws + 950400;      // 1024*64
    float* P1  = ws + 1015936;     // 256*64
    float* P2  = ws + 1032320;     // 256*64   (end 1048704 floats ~= 4.2 MB)

    k_cs<<<dim3(4),    dim3(256), 0, stream>>>(x, cs, CSp);
    k_tp<<<dim3(8192), dim3(256), 0, stream>>>(x, Wtp0, btp0, Wtp, btp, M8);
    k_s1<<<dim3(256),  dim3(256), 0, stream>>>(M8, cs, CSp, Wsp0, bsp0, SP1, P1);
    k_smid<<<dim3(256), dim3(256), 0, stream>>>(SP1, P1, M8, 5,  Wsp,         bsp,       SP2, P2);
    k_smid<<<dim3(256), dim3(256), 0, stream>>>(SP2, P2, M8, 37, Wsp + 16384, bsp + 64,  SP1, P1);
    k_slast<<<dim3(256), dim3(256), 0, stream>>>(SP1, P1, M8, 69, Wsp + 32768, bsp + 128,
                                                 x, Wfin, bfin, out);
}

// Round 8
// 106.659 us; speedup vs baseline: 4.8265x; 1.1270x over previous
//
#include <hip/hip_runtime.h>
#include <math.h>

// FermiNet_spin: N=1024, DIM=3, NP=5, NF=5, L=10, DEPTH=4, SPSIZE=64, TPSIZE=32
// k_tp v7: MFMA pair-stream, de-shuttled + poly-softplus + k-major LDS.
//   __launch_bounds__(256,4): 128-VGPR cap (LDS limits to 4 blocks/CU anyway)
//     -> weight frags/biases/accumulators stay in arch VGPRs, no AGPR shuttle.
//   softplus = max(x,0) + P5(exp(-|x|)), P5 = minimax log1p on (0,1]
//     (abs err ~1e-5; threshold 0.2) -> 1 trans op instead of 2.
//   feats LDS [8 kchunks][128 pairs][16B], tbuf [4 kchunks][64 rows][16B]:
//     all ds_read_b128 at bank start 4*(lm%8) -> 2-way only (free).
//   L1 bias via MFMA: feats half-35 = 1.0, W-frag k=35 = bt0 (bias as W row).
#define INV512f 0.001953125f
#define TPILf 0.628318530717958648f

typedef __attribute__((ext_vector_type(8))) _Float16 f16x8;
typedef __attribute__((ext_vector_type(4))) float f32x4;

__device__ __forceinline__ float sp_f(float v) {
    // softplus: max(v,0) + log1p(exp(-|v|)); log1p by deg-5 minimax on (0,1]
    float u = __expf(-fabsf(v));
    float p = u * fmaf(u, fmaf(u, fmaf(u, fmaf(u, 0.03215845f, -0.13606275f),
                                       0.28947478f), -0.49190896f), 0.99949556f);
    return fmaxf(v, 0.0f) + p;
}

__device__ __forceinline__ float wred64(float v) {
    v += __shfl_xor(v, 32, 64);
    v += __shfl_xor(v, 16, 64);
    v += __shfl_xor(v, 8, 64);
    v += __shfl_xor(v, 4, 64);
    v += __shfl_xor(v, 2, 64);
    v += __shfl_xor(v, 1, 64);
    return v;
}

__device__ __forceinline__ unsigned pkh(float a, float b) {
    return __builtin_bit_cast(unsigned, __builtin_amdgcn_cvt_pkrtz(a, b));
}

// A-frag: lane holds A[m=c][k=kbase+e] = W[k][c]; zeros for k>=Klim
__device__ __forceinline__ f16x8 wfrag(const float* __restrict__ W,
                                       int kbase, int c, int Klim) {
    f16x8 r;
#pragma unroll
    for (int e = 0; e < 8; ++e) {
        const int k = kbase + e;
        const float v = (k < Klim) ? W[k * 32 + c] : 0.f;
        r[e] = (_Float16)v;
    }
    return r;
}

// L1 high-K frag with bias folded at k==35 (pairs with constant-1 feature)
__device__ __forceinline__ f16x8 wfragL1hi(const float* __restrict__ W,
                                           const float* __restrict__ bias,
                                           int kbase, int c) {
    f16x8 r;
#pragma unroll
    for (int e = 0; e < 8; ++e) {
        const int k = kbase + e;
        const float v = (k < 35) ? W[k * 32 + c] : ((k == 35) ? bias[c] : 0.f);
        r[e] = (_Float16)v;
    }
    return r;
}

// ---------------------------------------------------------------------------
__global__ __launch_bounds__(256) void k_cs(
    const float* __restrict__ x, float* __restrict__ cs, float* __restrict__ CSp)
{
    __shared__ float wp[4][30];
    const int tid = threadIdx.x;
    const int i = (blockIdx.x << 8) + tid;
    float v[30];
    {
        float a0 = TPILf * x[3*i+0], a1 = TPILf * x[3*i+1], a2 = TPILf * x[3*i+2];
        float c1x = __cosf(a0), s1x = __sinf(a0);
        float c1y = __cosf(a1), s1y = __sinf(a1);
        float c1z = __cosf(a2), s1z = __sinf(a2);
        float cx = c1x, sx = s1x, cy = c1y, sy = s1y, cz = c1z, sz = s1z;
        v[0]=cx; v[1]=cy; v[2]=cz; v[3]=sx; v[4]=sy; v[5]=sz;
#pragma unroll
        for (int k = 2; k <= 5; ++k) {
            float ncx = cx*c1x - sx*s1x, nsx = sx*c1x + cx*s1x;
            float ncy = cy*c1y - sy*s1y, nsy = sy*c1y + cy*s1y;
            float ncz = cz*c1z - sz*s1z, nsz = sz*c1z + cz*s1z;
            cx=ncx; sx=nsx; cy=ncy; sy=nsy; cz=ncz; sz=nsz;
            const int base = (k-1)*6;
            v[base+0]=cx; v[base+1]=cy; v[base+2]=cz;
            v[base+3]=sx; v[base+4]=sy; v[base+5]=sz;
        }
    }
#pragma unroll
    for (int f = 0; f < 30; ++f) cs[(i << 5) + f] = v[f];
    const int w = tid >> 6;
#pragma unroll
    for (int f = 0; f < 30; ++f) {
        float t = wred64(v[f]);
        if ((tid & 63) == 0) wp[w][f] = t;
    }
    __syncthreads();
    if (tid < 30)
        CSp[(blockIdx.x << 5) + tid] = wp[0][tid] + wp[1][tid] + wp[2][tid] + wp[3][tid];
}

// ---------------------------------------------------------------------------
// LDS map (bytes):
//   feats : [8 kchunks][128 pairs][16]  @ 0      (16384B; chunks 5..7 zeroed,
//            chunk4 = halves 32..34 data, 35 = 1.0 bias slot, 36..39 = 0)
//   tbuf  : [4 kchunks][64 rows][16]    @ 16384  (4096B; row = wv*16+lm)
//   redp3 : [3][16][32] f32             @ 20480  (6144B)
//   rA0   : [2][5] f32                  @ 26624
// ---------------------------------------------------------------------------
__global__ __launch_bounds__(256, 4) void k_tp(
    const float* __restrict__ x,
    const float* __restrict__ Wt0, const float* __restrict__ bt0,
    const float* __restrict__ Wt,  const float* __restrict__ bt,
    float* __restrict__ M8)
{
    __shared__ __align__(16) float LDS[6672];
    char*  LDSC  = (char*)LDS;
    float* redp3 = LDS + 5120;
    float* rA0   = LDS + 6656;

    const int tid = threadIdx.x;
    const int i   = blockIdx.x >> 3;
    const int e8  = blockIdx.x & 7;

    // zero pad chunks 5..7 (6KB), all threads
#pragma unroll
    for (int z = tid; z < 384; z += 256)
        *(uint4*)(LDSC + 5*2048 + z*16) = make_uint4(0u, 0u, 0u, 0u);

    // ---- Phase A: lane = pair; 35 f16 features -> k-major LDS; d-power sums
    if (tid < 128) {
        const int j = (e8 << 7) + tid;
        const float r0 = x[3*i+0] - x[3*j+0];
        const float r1 = x[3*i+1] - x[3*j+1];
        const float r2 = x[3*i+2] - x[3*j+2];
        float c1x = __cosf(TPILf*r0), s1x = __sinf(TPILf*r0);
        float c1y = __cosf(TPILf*r1), s1y = __sinf(TPILf*r1);
        float c1z = __cosf(TPILf*r2), s1z = __sinf(TPILf*r2);
        float fb[35];
        // sin^2(t/2) identity: d2 = 1.5 - 0.5*(cos+cos+cos)
        float d2 = fmaxf(1.5f - 0.5f*(c1x + c1y + c1z), 0.0f);
        float d1 = sqrtf(d2);
        fb[0]=d1; fb[1]=d2; fb[2]=d2*d1; fb[3]=d2*d2; fb[4]=d2*d2*d1;
        float cx=c1x,sx=s1x,cy=c1y,sy=s1y,cz=c1z,sz=s1z;
        fb[5]=cx; fb[6]=cy; fb[7]=cz; fb[8]=sx; fb[9]=sy; fb[10]=sz;
#pragma unroll
        for (int k = 2; k <= 5; ++k) {
            float ncx = cx*c1x - sx*s1x, nsx = sx*c1x + cx*s1x;
            float ncy = cy*c1y - sy*s1y, nsy = sy*c1y + cy*s1y;
            float ncz = cz*c1z - sz*s1z, nsz = sz*c1z + cz*s1z;
            cx=ncx; sx=nsx; cy=ncy; sy=nsy; cz=ncz; sz=nsz;
            const int base = 5 + (k-1)*6;
            fb[base+0]=cx; fb[base+1]=cy; fb[base+2]=cz;
            fb[base+3]=sx; fb[base+4]=sy; fb[base+5]=sz;
        }
        unsigned wds[17];
#pragma unroll
        for (int q2 = 0; q2 < 17; ++q2) wds[q2] = pkh(fb[2*q2], fb[2*q2+1]);
        *(uint4*)(LDSC + 0*2048 + tid*16) = make_uint4(wds[0], wds[1], wds[2], wds[3]);
        *(uint4*)(LDSC + 1*2048 + tid*16) = make_uint4(wds[4], wds[5], wds[6], wds[7]);
        *(uint4*)(LDSC + 2*2048 + tid*16) = make_uint4(wds[8], wds[9], wds[10], wds[11]);
        *(uint4*)(LDSC + 3*2048 + tid*16) = make_uint4(wds[12], wds[13], wds[14], wds[15]);
        *(uint4*)(LDSC + 4*2048 + tid*16) = make_uint4(wds[16], pkh(fb[34], 1.0f), 0u, 0u);
        // d-power sums (per 64-pair wave)
        const int w2 = tid >> 6;
        float s;
        s = wred64(fb[0]); if ((tid & 63) == 0) rA0[w2*5+0] = s;
        s = wred64(fb[1]); if ((tid & 63) == 0) rA0[w2*5+1] = s;
        s = wred64(fb[2]); if ((tid & 63) == 0) rA0[w2*5+2] = s;
        s = wred64(fb[3]); if ((tid & 63) == 0) rA0[w2*5+3] = s;
        s = wred64(fb[4]); if ((tid & 63) == 0) rA0[w2*5+4] = s;
    }
    __syncthreads();

    const int l  = tid & 63;
    const int wv = tid >> 6;
    const int lm = l & 15;    // pair-in-group (n) / col-within-half for A
    const int lq = l >> 4;    // k-chunk

    // weight A-frags (global, L2-cached; built once). L1 bias folded at k=35.
    f16x8 a1a0 = wfrag(Wt0,        lq*8,      lm,      35);
    f16x8 a1b0 = wfrag(Wt0,        lq*8,      lm + 16, 35);
    f16x8 a1a1 = wfragL1hi(Wt0, bt0, 32 + lq*8, lm);
    f16x8 a1b1 = wfragL1hi(Wt0, bt0, 32 + lq*8, lm + 16);
    f16x8 a2a  = wfrag(Wt,         lq*8,      lm,      32);
    f16x8 a2b  = wfrag(Wt,         lq*8,      lm + 16, 32);
    f16x8 a3a  = wfrag(Wt + 1024,  lq*8,      lm,      32);
    f16x8 a3b  = wfrag(Wt + 1024,  lq*8,      lm + 16, 32);

    float b2a[4], b2b[4], b3a[4], b3b[4];
    {
        float4 t;
        t = *(const float4*)&bt[lq*4];       b2a[0]=t.x; b2a[1]=t.y; b2a[2]=t.z; b2a[3]=t.w;
        t = *(const float4*)&bt[16+lq*4];    b2b[0]=t.x; b2b[1]=t.y; b2b[2]=t.z; b2b[3]=t.w;
        t = *(const float4*)&bt[32+lq*4];    b3a[0]=t.x; b3a[1]=t.y; b3a[2]=t.z; b3a[3]=t.w;
        t = *(const float4*)&bt[48+lq*4];    b3b[0]=t.x; b3b[1]=t.y; b3b[2]=t.z; b3b[3]=t.w;
    }

    float A1[8], A2[8], A3[8];
#pragma unroll
    for (int q = 0; q < 8; ++q) { A1[q]=0.f; A2[q]=0.f; A3[q]=0.f; }

    const int row16 = (wv << 4) + lm;
    char* twr = LDSC + 16384 + (lq >> 1)*1024 + row16*16 + (lq & 1)*8;

#pragma unroll 1
    for (int g = 0; g < 2; ++g) {
        const int prow = (wv << 5) + (g << 4) + lm;
        f16x8 bf0 = *(const f16x8*)(LDSC + lq*2048 + prow*16);        // k 0..31
        f16x8 bf1 = *(const f16x8*)(LDSC + (lq+4)*2048 + prow*16);    // k 32..63

        // L1: D = W1^T (35x32, K-padded, bias row 35) x feats^T
        f32x4 d0a = {0.f,0.f,0.f,0.f}, d0b = {0.f,0.f,0.f,0.f};
        d0a = __builtin_amdgcn_mfma_f32_16x16x32_f16(a1a0, bf0, d0a, 0, 0, 0);
        d0a = __builtin_amdgcn_mfma_f32_16x16x32_f16(a1a1, bf1, d0a, 0, 0, 0);
        d0b = __builtin_amdgcn_mfma_f32_16x16x32_f16(a1b0, bf0, d0b, 0, 0, 0);
        d0b = __builtin_amdgcn_mfma_f32_16x16x32_f16(a1b1, bf1, d0b, 0, 0, 0);

        float t1v[8];
#pragma unroll
        for (int q = 0; q < 4; ++q) {
            t1v[q]   = sp_f(d0a[q]);  A1[q]   += t1v[q];
            t1v[4+q] = sp_f(d0b[q]);  A1[4+q] += t1v[4+q];
        }
        *(uint2*)twr          = make_uint2(pkh(t1v[0], t1v[1]), pkh(t1v[2], t1v[3]));
        *(uint2*)(twr + 2048) = make_uint2(pkh(t1v[4], t1v[5]), pkh(t1v[6], t1v[7]));
        asm volatile("" ::: "memory");

        // L2
        f16x8 btf = *(const f16x8*)(LDSC + 16384 + lq*1024 + row16*16);
        f32x4 d2a_ = {0.f,0.f,0.f,0.f}, d2b_ = {0.f,0.f,0.f,0.f};
        d2a_ = __builtin_amdgcn_mfma_f32_16x16x32_f16(a2a, btf, d2a_, 0, 0, 0);
        d2b_ = __builtin_amdgcn_mfma_f32_16x16x32_f16(a2b, btf, d2b_, 0, 0, 0);
        float t2v[8];
#pragma unroll
        for (int q = 0; q < 4; ++q) {
            t2v[q]   = t1v[q]   + sp_f(d2a_[q] + b2a[q]);  A2[q]   += t2v[q];
            t2v[4+q] = t1v[4+q] + sp_f(d2b_[q] + b2b[q]);  A2[4+q] += t2v[4+q];
        }
        *(uint2*)twr          = make_uint2(pkh(t2v[0], t2v[1]), pkh(t2v[2], t2v[3]));
        *(uint2*)(twr + 2048) = make_uint2(pkh(t2v[4], t2v[5]), pkh(t2v[6], t2v[7]));
        asm volatile("" ::: "memory");

        // L3 (sums only)
        f16x8 btg = *(const f16x8*)(LDSC + 16384 + lq*1024 + row16*16);
        f32x4 d3a_ = {0.f,0.f,0.f,0.f}, d3b_ = {0.f,0.f,0.f,0.f};
        d3a_ = __builtin_amdgcn_mfma_f32_16x16x32_f16(a3a, btg, d3a_, 0, 0, 0);
        d3b_ = __builtin_amdgcn_mfma_f32_16x16x32_f16(a3b, btg, d3b_, 0, 0, 0);
#pragma unroll
        for (int q = 0; q < 4; ++q) {
            A3[q]   += t2v[q]   + sp_f(d3a_[q] + b3a[q]);
            A3[4+q] += t2v[4+q] + sp_f(d3b_[q] + b3b[q]);
        }
    }

    // ---- reduce over pairs: 2-step butterfly (lm bits 0,1), then LDS tree
#pragma unroll
    for (int q = 0; q < 8; ++q) {
        A1[q] += __shfl_xor(A1[q], 1, 64);  A1[q] += __shfl_xor(A1[q], 2, 64);
        A2[q] += __shfl_xor(A2[q], 1, 64);  A2[q] += __shfl_xor(A2[q], 2, 64);
        A3[q] += __shfl_xor(A3[q], 1, 64);  A3[q] += __shfl_xor(A3[q], 2, 64);
    }
    if ((lm & 3) == 0) {
        const int grp = lm >> 2;
        const int base0 = ((0*4 + wv)*4 + grp)*32;
        const int base1 = ((1*4 + wv)*4 + grp)*32;
        const int base2 = ((2*4 + wv)*4 + grp)*32;
        *(float4*)&redp3[base0 + lq*4]      = make_float4(A1[0], A1[1], A1[2], A1[3]);
        *(float4*)&redp3[base0 + 16 + lq*4] = make_float4(A1[4], A1[5], A1[6], A1[7]);
        *(float4*)&redp3[base1 + lq*4]      = make_float4(A2[0], A2[1], A2[2], A2[3]);
        *(float4*)&redp3[base1 + 16 + lq*4] = make_float4(A2[4], A2[5], A2[6], A2[7]);
        *(float4*)&redp3[base2 + lq*4]      = make_float4(A3[0], A3[1], A3[2], A3[3]);
        *(float4*)&redp3[base2 + 16 + lq*4] = make_float4(A3[4], A3[5], A3[6], A3[7]);
    }
    __syncthreads();

    float* M8e = M8 + ((size_t)i*8 + e8)*104;
    if (tid < 96) {
        const int layer = tid >> 5, c = tid & 31;
        float s = 0.f;
#pragma unroll
        for (int w2 = 0; w2 < 16; ++w2)
            s += redp3[(layer*16 + w2)*32 + c];
        M8e[5 + layer*32 + c] = s;
    }
    if (tid < 5)
        M8e[tid] = rA0[tid] + rA0[5 + tid];
}

// ---------------------------------------------------------------------------
// k_s1: sp1 = softplus(f0 @ Wsp0 + b); Fourier tp-sums reconstructed from cs/CSp
// ---------------------------------------------------------------------------
__global__ __launch_bounds__(256) void k_s1(
    const float* __restrict__ M8, const float* __restrict__ cs,
    const float* __restrict__ CSp,
    const float* __restrict__ W, const float* __restrict__ bv,
    float* __restrict__ SP1, float* __restrict__ P1)
{
    __shared__ float CSsh[2][30];
    __shared__ float feat[4][70];
    __shared__ float red[4][64];
    const int tid = threadIdx.x;
    const int c = tid & 63, g = tid >> 6;
    const int ii = (blockIdx.x << 2) + g;

    if (tid < 60) {
        int hh = tid / 30, f = tid - 30*hh;
        CSsh[hh][f] = CSp[(hh << 6) + f] + CSp[(hh << 6) + 32 + f];
    }
    __syncthreads();
#pragma unroll
    for (int pass = 0; pass < 2; ++pass) {
        const int f = (pass == 0) ? c : 64 + c;
        if (pass == 0 || c < 6) {
            const int sec = (f >= 35) ? 1 : 0;
            const int idx = f - 35*sec;
            float v;
            if (idx < 5) {
                const float* mp = M8 + ((size_t)ii*8 + sec*4)*104 + idx;
                v = mp[0] + mp[104] + mp[208] + mp[312];
            } else {
                const int gg = idx - 5;
                const int k = gg / 6;
                const int m = gg - 6*k;
                const int dim = (m < 3) ? m : m - 3;
                const float cth = cs[(ii << 5) + k*6 + dim];
                const float sth = cs[(ii << 5) + k*6 + 3 + dim];
                const float Cc  = CSsh[sec][k*6 + dim];
                const float Sc  = CSsh[sec][k*6 + 3 + dim];
                v = (m < 3) ? fmaf(cth, Cc, sth*Sc) : (sth*Cc - cth*Sc);
            }
            feat[g][f] = v * INV512f;
        }
    }
    __syncthreads();
    float acc = bv[c];
#pragma unroll 7
    for (int f = 0; f < 70; ++f)
        acc = fmaf(feat[g][f], W[(9 + f)*64 + c], acc);
    float s = sp_f(acc);
    SP1[(ii << 6) + c] = s;
    red[g][c] = s;
    __syncthreads();
    if (g == 0)
        P1[(blockIdx.x << 6) + c] = red[0][c] + red[1][c] + red[2][c] + red[3][c];
}

// ---------------------------------------------------------------------------
__device__ __forceinline__ float spmid_core(
    int b, int tid,
    const float* __restrict__ SPin, const float* __restrict__ Pin,
    const float* __restrict__ M8, int loff,
    const float* __restrict__ W, const float* __restrict__ bv,
    float Sred[2][4][64], float Ssh[2][64], float si[4][64], float featm[4][64])
{
    const int c = tid & 63, g = tid >> 6;
    const int ii = (b << 2) + g;
    float pu = 0.f, pd = 0.f;
#pragma unroll 4
    for (int bb = g; bb < 128; bb += 4) {
        pu += Pin[(bb << 6) + c];
        pd += Pin[((128 + bb) << 6) + c];
    }
    si[g][c] = SPin[(ii << 6) + c];
    {
        const int h = c >> 5, cc = c & 31;
        const float* mp = M8 + ((size_t)ii*8 + h*4)*104 + loff + cc;
        featm[g][c] = (mp[0] + mp[104] + mp[208] + mp[312]) * INV512f;
    }
    Sred[0][g][c] = pu; Sred[1][g][c] = pd;
    __syncthreads();
    if (g < 2)
        Ssh[g][c] = (Sred[g][0][c] + Sred[g][1][c] + Sred[g][2][c] + Sred[g][3][c]) * INV512f;
    __syncthreads();
    float acc = bv[c];
#pragma unroll 8
    for (int k = 0; k < 64; ++k) acc = fmaf(si[g][k],    W[(k << 6) + c],         acc);
#pragma unroll 8
    for (int k = 0; k < 64; ++k) acc = fmaf(Ssh[0][k],   W[((64 + k) << 6) + c],  acc);
#pragma unroll 8
    for (int k = 0; k < 64; ++k) acc = fmaf(Ssh[1][k],   W[((128 + k) << 6) + c], acc);
#pragma unroll 8
    for (int k = 0; k < 64; ++k) acc = fmaf(featm[g][k], W[((192 + k) << 6) + c], acc);
    return si[g][c] + sp_f(acc);
}

__global__ __launch_bounds__(256) void k_smid(
    const float* __restrict__ SPin, const float* __restrict__ Pin,
    const float* __restrict__ M8, int loff,
    const float* __restrict__ W, const float* __restrict__ bv,
    float* __restrict__ SPout, float* __restrict__ Pout)
{
    __shared__ float Sred[2][4][64];
    __shared__ float Ssh[2][64];
    __shared__ float si[4][64];
    __shared__ float featm[4][64];
    const int tid = threadIdx.x;
    float s = spmid_core(blockIdx.x, tid, SPin, Pin, M8, loff, W, bv, Sred, Ssh, si, featm);
    const int c = tid & 63, g = tid >> 6;
    SPout[(((blockIdx.x << 2) + g) << 6) + c] = s;
    __syncthreads();
    Sred[0][g][c] = s;
    __syncthreads();
    if (g == 0)
        Pout[(blockIdx.x << 6) + c] = Sred[0][0][c] + Sred[0][1][c] + Sred[0][2][c] + Sred[0][3][c];
}

__global__ __launch_bounds__(256) void k_slast(
    const float* __restrict__ SPin, const float* __restrict__ Pin,
    const float* __restrict__ M8, int loff,
    const float* __restrict__ W, const float* __restrict__ bv,
    const float* __restrict__ x,
    const float* __restrict__ Wfin, const float* __restrict__ bfin,
    float* __restrict__ out)
{
    __shared__ float Sred[2][4][64];
    __shared__ float Ssh[2][64];
    __shared__ float si[4][64];
    __shared__ float featm[4][64];
    const int tid = threadIdx.x;
    float s = spmid_core(blockIdx.x, tid, SPin, Pin, M8, loff, W, bv, Sred, Ssh, si, featm);
    const int c = tid & 63, g = tid >> 6;
    __syncthreads();
    si[g][c] = s;   // sp4 rows
    __syncthreads();
    if (tid < 12) {
        const int r = tid / 3, d = tid - 3*r;
        const int io = (blockIdx.x << 2) + r;
        float acc = x[3*io + d] + bfin[d];
#pragma unroll 16
        for (int k = 0; k < 64; ++k) acc = fmaf(si[r][k], Wfin[3*k + d], acc);
        out[3*io + d] = acc;
    }
}

extern "C" void kernel_launch(void* const* d_in, const int* in_sizes, int n_in,
                              void* d_out, int out_size, void* d_ws, size_t ws_size,
                              hipStream_t stream)
{
    const float* x    = (const float*)d_in[0];
    const float* Wsp0 = (const float*)d_in[1];
    const float* bsp0 = (const float*)d_in[2];
    const float* Wsp  = (const float*)d_in[3];   // (3, 256, 64)
    const float* bsp  = (const float*)d_in[4];   // (3, 64)
    const float* Wtp0 = (const float*)d_in[5];   // (35, 32)
    const float* btp0 = (const float*)d_in[6];
    const float* Wtp  = (const float*)d_in[7];   // (2, 32, 32)
    const float* btp  = (const float*)d_in[8];   // (2, 32)
    const float* Wfin = (const float*)d_in[9];   // (64, 3)
    const float* bfin = (const float*)d_in[10];
    float* out = (float*)d_out;
    float* ws  = (float*)d_ws;

    // workspace layout (floats)
    float* cs  = ws;               // 1024*32      = 32768
    float* CSp = ws + 32768;       // 4*32         = 128
    float* M8  = ws + 32896;       // 1024*8*104   = 851968
    float* SP1 = ws + 884864;      // 1024*64
    float* SP2 = ws + 950400;      // 1024*64
    float* P1  = ws + 1015936;     // 256*64
    float* P2  = ws + 1032320;     // 256*64   (end 1048704 floats ~= 4.2 MB)

    k_cs<<<dim3(4),    dim3(256), 0, stream>>>(x, cs, CSp);
    k_tp<<<dim3(8192), dim3(256), 0, stream>>>(x, Wtp0, btp0, Wtp, btp, M8);
    k_s1<<<dim3(256),  dim3(256), 0, stream>>>(M8, cs, CSp, Wsp0, bsp0, SP1, P1);
    k_smid<<<dim3(256), dim3(256), 0, stream>>>(SP1, P1, M8, 5,  Wsp,         bsp,       SP2, P2);
    k_smid<<<dim3(256), dim3(256), 0, stream>>>(SP2, P2, M8, 37, Wsp + 16384, bsp + 64,  SP1, P1);
    k_slast<<<dim3(256), dim3(256), 0, stream>>>(SP1, P1, M8, 69, Wsp + 32768, bsp + 128,
                                                 x, Wfin, bfin, out);
}